// Round 1
// baseline (4675.700 us; speedup 1.0000x reference)
//
#include <hip/hip_runtime.h>
#include <math.h>

#define Bsz 128
#define Hh 14
#define Ww 14
#define Nn 196
#define Cc 768
#define Gg 8
#define CgC 96
#define NHh 12
#define Dh 64
#define ROWS (Bsz*Nn)   // 25088

// ---------------------------------------------------------------------------
// GEMM: C[r][o] = sum_c A[r][c]*W[o][c] + bias[o]
// A: (ROWS x 768) row-major, W: (768 x 768) row-major, C: (ROWS x 768)
// 128x128 tile, BK=16, 256 threads, 8x8 per thread.
// ---------------------------------------------------------------------------
__global__ __launch_bounds__(256) void gemm_nt_bias(
    const float* __restrict__ A, const float* __restrict__ W,
    const float* __restrict__ bias, float* __restrict__ C)
{
  __shared__ __align__(16) float As[16][132];
  __shared__ __align__(16) float Ws[16][132];
  const int tid = threadIdx.x;
  const int tx = tid & 15;        // n dir
  const int ty = tid >> 4;        // m dir
  const int row0 = blockIdx.x * 128;
  const int col0 = blockIdx.y * 128;
  const int lr = tid >> 1;            // 0..127
  const int lk = (tid & 1) * 8;       // 0 or 8

  const float* Ap = A + (size_t)(row0 + lr) * Cc + lk;
  const float* Wp = W + (size_t)(col0 + lr) * Cc + lk;

  float acc[8][8];
#pragma unroll
  for (int i = 0; i < 8; ++i)
#pragma unroll
    for (int j = 0; j < 8; ++j) acc[i][j] = 0.f;

  for (int k0 = 0; k0 < Cc; k0 += 16) {
    float4 av0 = *(const float4*)(Ap + k0);
    float4 av1 = *(const float4*)(Ap + k0 + 4);
    float4 wv0 = *(const float4*)(Wp + k0);
    float4 wv1 = *(const float4*)(Wp + k0 + 4);
    As[lk+0][lr]=av0.x; As[lk+1][lr]=av0.y; As[lk+2][lr]=av0.z; As[lk+3][lr]=av0.w;
    As[lk+4][lr]=av1.x; As[lk+5][lr]=av1.y; As[lk+6][lr]=av1.z; As[lk+7][lr]=av1.w;
    Ws[lk+0][lr]=wv0.x; Ws[lk+1][lr]=wv0.y; Ws[lk+2][lr]=wv0.z; Ws[lk+3][lr]=wv0.w;
    Ws[lk+4][lr]=wv1.x; Ws[lk+5][lr]=wv1.y; Ws[lk+6][lr]=wv1.z; Ws[lk+7][lr]=wv1.w;
    __syncthreads();
#pragma unroll
    for (int kk = 0; kk < 16; ++kk) {
      float a_[8], b_[8];
      *(float4*)&a_[0] = *(const float4*)&As[kk][ty*8];
      *(float4*)&a_[4] = *(const float4*)&As[kk][ty*8+4];
      *(float4*)&b_[0] = *(const float4*)&Ws[kk][tx*8];
      *(float4*)&b_[4] = *(const float4*)&Ws[kk][tx*8+4];
#pragma unroll
      for (int i = 0; i < 8; ++i)
#pragma unroll
        for (int j = 0; j < 8; ++j)
          acc[i][j] = fmaf(a_[i], b_[j], acc[i][j]);
    }
    __syncthreads();
  }

  float4 bv0 = *(const float4*)(bias + col0 + tx*8);
  float4 bv1 = *(const float4*)(bias + col0 + tx*8 + 4);
  float bb[8];
  *(float4*)&bb[0] = bv0; *(float4*)&bb[4] = bv1;
#pragma unroll
  for (int i = 0; i < 8; ++i) {
    float o0[4], o1[4];
#pragma unroll
    for (int j = 0; j < 4; ++j) { o0[j] = acc[i][j] + bb[j]; o1[j] = acc[i][j+4] + bb[j+4]; }
    float* crow = C + (size_t)(row0 + ty*8 + i) * Cc + col0 + tx*8;
    *(float4*)crow       = *(float4*)&o0[0];
    *(float4*)(crow + 4) = *(float4*)&o1[0];
  }
}

// ---------------------------------------------------------------------------
// Fused offset network + bilinear sampling.
// One block of 128 threads per site (b,g,n).  Threads 0..95 own channel cg.
// dwconv3x3(Q) -> LN over 96ch -> GELU(exact) -> pointwise->2 -> tanh/13 ->
// grid position -> bilinear sample of hidden -> XS[b][n][g*96+cg]
// ---------------------------------------------------------------------------
__global__ __launch_bounds__(128) void offset_sample(
    const float* __restrict__ Q, const float* __restrict__ hidden,
    const float* __restrict__ dw_w, const float* __restrict__ dw_b,
    const float* __restrict__ ln_w, const float* __restrict__ ln_b,
    const float* __restrict__ pw_w, float* __restrict__ XS)
{
  __shared__ float red[128];
  __shared__ float gxy[2];
  const int site = blockIdx.x;          // (b*G+g)*N + n
  const int n = site % Nn;
  const int bg = site / Nn;
  const int g = bg % Gg;
  const int b = bg / Gg;
  const int h = n / Ww, w = n % Ww;
  const int tid = threadIdx.x;

  float tval = 0.f;
  if (tid < CgC) {
    tval = dw_b[tid];
    const float* wp = dw_w + tid * 9;
    const float* qb = Q + (size_t)b * Nn * Cc + g * CgC + tid;
#pragma unroll
    for (int ky = 0; ky < 3; ++ky) {
      int hhp = h + ky - 1;
      if (hhp < 0 || hhp > Hh - 1) continue;
#pragma unroll
      for (int kx = 0; kx < 3; ++kx) {
        int wwp = w + kx - 1;
        if (wwp < 0 || wwp > Ww - 1) continue;
        tval = fmaf(qb[(size_t)(hhp * Ww + wwp) * Cc], wp[ky * 3 + kx], tval);
      }
    }
  }
  // mean
  red[tid] = (tid < CgC) ? tval : 0.f;
  __syncthreads();
  for (int s = 64; s > 0; s >>= 1) { if (tid < s) red[tid] += red[tid + s]; __syncthreads(); }
  float mu = red[0] * (1.f / 96.f);
  __syncthreads();
  // var
  float dv = (tid < CgC) ? (tval - mu) : 0.f;
  red[tid] = dv * dv;
  __syncthreads();
  for (int s = 64; s > 0; s >>= 1) { if (tid < s) red[tid] += red[tid + s]; __syncthreads(); }
  float rstd = rsqrtf(red[0] * (1.f / 96.f) + 1e-5f);
  __syncthreads();

  float a = 0.f;
  if (tid < CgC) {
    float tn = (tval - mu) * rstd * ln_w[tid] + ln_b[tid];
    a = 0.5f * tn * (1.f + erff(tn * 0.70710678118654752f));   // exact gelu
  }
  red[tid] = (tid < CgC) ? a * pw_w[tid] : 0.f;
  __syncthreads();
  for (int s = 64; s > 0; s >>= 1) { if (tid < s) red[tid] += red[tid + s]; __syncthreads(); }
  float o0 = red[0];
  __syncthreads();
  red[tid] = (tid < CgC) ? a * pw_w[CgC + tid] : 0.f;
  __syncthreads();
  for (int s = 64; s > 0; s >>= 1) { if (tid < s) red[tid] += red[tid + s]; __syncthreads(); }
  float o1 = red[0];

  if (tid == 0) {
    float offy = tanhf(o0) * (1.f / 13.f);
    float offx = tanhf(o1) * (1.f / 13.f);
    float refy = (h + 0.5f) / 14.f * 2.f - 1.f;
    float refx = (w + 0.5f) / 14.f * 2.f - 1.f;
    float py = offy + refy;
    float px = offx + refx;
    gxy[0] = (px + 1.f) * 0.5f * 13.f;   // gx
    gxy[1] = (py + 1.f) * 0.5f * 13.f;   // gy
  }
  __syncthreads();

  if (tid < CgC) {
    float gx = gxy[0], gy = gxy[1];
    float x0f = floorf(gx), y0f = floorf(gy);
    int x0 = (int)x0f, y0 = (int)y0f;
    float wx1 = gx - x0f, wx0 = 1.f - wx1;
    float wy1 = gy - y0f, wy0 = 1.f - wy1;
    const float* hb = hidden + (size_t)b * Nn * Cc + g * CgC + tid;
    float acc = 0.f;
    if (x0 >= 0 && x0 <= 13 && y0 >= 0 && y0 <= 13)       acc = fmaf(wx0 * wy0, hb[(size_t)(y0 * Ww + x0) * Cc], acc);
    if (x0+1 >= 0 && x0+1 <= 13 && y0 >= 0 && y0 <= 13)   acc = fmaf(wx1 * wy0, hb[(size_t)(y0 * Ww + x0 + 1) * Cc], acc);
    if (x0 >= 0 && x0 <= 13 && y0+1 >= 0 && y0+1 <= 13)   acc = fmaf(wx0 * wy1, hb[(size_t)((y0 + 1) * Ww + x0) * Cc], acc);
    if (x0+1 >= 0 && x0+1 <= 13 && y0+1 >= 0 && y0+1 <= 13) acc = fmaf(wx1 * wy1, hb[(size_t)((y0 + 1) * Ww + x0 + 1) * Cc], acc);
    XS[((size_t)b * Nn + n) * Cc + g * CgC + tid] = acc;
  }
}

// ---------------------------------------------------------------------------
// Attention scores + softmax.  Block per (b, head, m-chunk of 14).
// K slice staged transposed in LDS (conflict-free scalar dot).
// attn[b,h,m,n] written to d_out's second region.
// ---------------------------------------------------------------------------
__global__ __launch_bounds__(256) void attn_scores(
    const float* __restrict__ Qm, const float* __restrict__ Km,
    float* __restrict__ attn)
{
  __shared__ float Kl[64][201];
  __shared__ float ql[64];
  __shared__ float red[256];
  const int tid = threadIdx.x;
  const int mc = blockIdx.x;   // 0..13
  const int hh = blockIdx.y;   // 0..11
  const int b  = blockIdx.z;   // 0..127

  const float* Kbase = Km + (size_t)b * Nn * Cc + hh * Dh;
  for (int idx = tid; idx < Nn * Dh; idx += 256) {
    int n = idx >> 6, d = idx & 63;
    Kl[d][n] = Kbase[(size_t)n * Cc + d];
  }
  __syncthreads();

  for (int mi = 0; mi < 14; ++mi) {
    int m = mc * 14 + mi;
    if (tid < Dh) ql[tid] = Qm[((size_t)b * Nn + m) * Cc + hh * Dh + tid];
    __syncthreads();
    float s = 0.f;
    if (tid < Nn) {
#pragma unroll
      for (int d = 0; d < Dh; ++d) s = fmaf(ql[d], Kl[d][tid], s);
      s *= 0.125f;
    }
    red[tid] = (tid < Nn) ? s : -1e30f;
    __syncthreads();
    for (int st = 128; st > 0; st >>= 1) { if (tid < st) red[tid] = fmaxf(red[tid], red[tid + st]); __syncthreads(); }
    float mx = red[0];
    __syncthreads();
    float p = (tid < Nn) ? expf(s - mx) : 0.f;
    red[tid] = p;
    __syncthreads();
    for (int st = 128; st > 0; st >>= 1) { if (tid < st) red[tid] += red[tid + st]; __syncthreads(); }
    float inv = 1.f / red[0];
    __syncthreads();
    if (tid < Nn)
      attn[(((size_t)b * NHh + hh) * Nn + m) * Nn + tid] = p * inv;
  }
}

// ---------------------------------------------------------------------------
// PV: OUT[b][m][h*64+d] = sum_n attn[b,h,m,n] * V[b][n][h*64+d]
// Block per (b, head); V slice in LDS.
// ---------------------------------------------------------------------------
__global__ __launch_bounds__(256) void attn_pv(
    const float* __restrict__ attn, const float* __restrict__ Vm,
    float* __restrict__ OUT)
{
  __shared__ float Vl[196][65];
  const int hh = blockIdx.x;
  const int b  = blockIdx.y;
  const int tid = threadIdx.x;
  const float* Vbase = Vm + (size_t)b * Nn * Cc + hh * Dh;
  for (int idx = tid; idx < Nn * Dh; idx += 256) {
    int n = idx >> 6, d = idx & 63;
    Vl[n][d] = Vbase[(size_t)n * Cc + d];
  }
  __syncthreads();
  const int d = tid & 63, mq = tid >> 6;    // mq 0..3
  for (int m0 = 0; m0 < Nn; m0 += 4) {
    int m = m0 + mq;
    const float* arow = attn + (((size_t)b * NHh + hh) * Nn + m) * Nn;
    float acc = 0.f;
#pragma unroll 4
    for (int n = 0; n < Nn; ++n) acc = fmaf(arow[n], Vl[n][d], acc);
    OUT[((size_t)b * Nn + m) * Cc + hh * Dh + d] = acc;
  }
}

// ---------------------------------------------------------------------------
extern "C" void kernel_launch(void* const* d_in, const int* in_sizes, int n_in,
                              void* d_out, int out_size, void* d_ws, size_t ws_size,
                              hipStream_t stream) {
  const float* hidden = (const float*)d_in[0];
  const float* Wq = (const float*)d_in[1];
  const float* bq = (const float*)d_in[2];
  const float* dw_w = (const float*)d_in[3];
  const float* dw_b = (const float*)d_in[4];
  const float* ln_w = (const float*)d_in[5];
  const float* ln_b = (const float*)d_in[6];
  const float* pw_w = (const float*)d_in[7];
  const float* Wk = (const float*)d_in[8];
  const float* bk = (const float*)d_in[9];
  const float* Wv = (const float*)d_in[10];
  const float* bv = (const float*)d_in[11];
  const float* Wp = (const float*)d_in[12];
  const float* bp = (const float*)d_in[13];
  const float* Wo = (const float*)d_in[14];
  const float* bo = (const float*)d_in[15];

  const size_t SZ = (size_t)Bsz * Nn * Cc;      // 19,267,584
  float* yout = (float*)d_out;                  // (B,N,C)
  float* attn = yout + SZ;                      // (B,12,196,196)

  float* Q  = (float*)d_ws;                     // (B,N,C)  later reused as Y1
  float* XS = Q + SZ;                           // (B,N,C)  later reused as OUT
  float* Kb = XS + SZ;
  float* Vb = Kb + SZ;

  dim3 gg(ROWS / 128, Cc / 128);                // (196, 6)

  // 1. Q = hidden @ Wq^T + bq
  gemm_nt_bias<<<gg, 256, 0, stream>>>(hidden, Wq, bq, Q);
  // 2. offset network + bilinear sampling -> XS
  offset_sample<<<Bsz * Gg * Nn, 128, 0, stream>>>(Q, hidden, dw_w, dw_b, ln_w, ln_b, pw_w, XS);
  // 3./4. K,V
  gemm_nt_bias<<<gg, 256, 0, stream>>>(XS, Wk, bk, Kb);
  gemm_nt_bias<<<gg, 256, 0, stream>>>(XS, Wv, bv, Vb);
  // 5. scores + softmax -> attn (output region)
  attn_scores<<<dim3(14, NHh, Bsz), 256, 0, stream>>>(Q, Kb, attn);
  // 6. PV -> OUT (reuse XS)
  attn_pv<<<dim3(NHh, Bsz), 256, 0, stream>>>(attn, Vb, XS);
  // 7. Y1 = OUT @ Wproj^T + bproj (reuse Q)
  gemm_nt_bias<<<gg, 256, 0, stream>>>(XS, Wp, bp, Q);
  // 8. y = Y1 @ Wout^T + bout -> d_out
  gemm_nt_bias<<<gg, 256, 0, stream>>>(Q, Wo, bo, yout);
}

// Round 2
// 3150.621 us; speedup vs baseline: 1.4841x; 1.4841x over previous
//
#include <hip/hip_runtime.h>
#include <math.h>

#define Bsz 128
#define Hh 14
#define Ww 14
#define Nn 196
#define Cc 768
#define Gg 8
#define CgC 96
#define NHh 12
#define Dh 64
#define ROWS (Bsz*Nn)   // 25088

// ---------------------------------------------------------------------------
// GEMM: C[r][o] = sum_c A[r][c]*W[o][c] + bias[o]
// A: (ROWS x 768) row-major, W: (768 x 768) row-major, C: (ROWS x 768)
// 128x128 tile, BK=16, 256 threads, 8x8 per thread.
// ---------------------------------------------------------------------------
__global__ __launch_bounds__(256) void gemm_nt_bias(
    const float* __restrict__ A, const float* __restrict__ W,
    const float* __restrict__ bias, float* __restrict__ C)
{
  __shared__ __align__(16) float As[16][132];
  __shared__ __align__(16) float Ws[16][132];
  const int tid = threadIdx.x;
  const int tx = tid & 15;        // n dir
  const int ty = tid >> 4;        // m dir
  const int row0 = blockIdx.x * 128;
  const int col0 = blockIdx.y * 128;
  const int lr = tid >> 1;            // 0..127
  const int lk = (tid & 1) * 8;       // 0 or 8

  const float* Ap = A + (size_t)(row0 + lr) * Cc + lk;
  const float* Wp = W + (size_t)(col0 + lr) * Cc + lk;

  float acc[8][8];
#pragma unroll
  for (int i = 0; i < 8; ++i)
#pragma unroll
    for (int j = 0; j < 8; ++j) acc[i][j] = 0.f;

  for (int k0 = 0; k0 < Cc; k0 += 16) {
    float4 av0 = *(const float4*)(Ap + k0);
    float4 av1 = *(const float4*)(Ap + k0 + 4);
    float4 wv0 = *(const float4*)(Wp + k0);
    float4 wv1 = *(const float4*)(Wp + k0 + 4);
    As[lk+0][lr]=av0.x; As[lk+1][lr]=av0.y; As[lk+2][lr]=av0.z; As[lk+3][lr]=av0.w;
    As[lk+4][lr]=av1.x; As[lk+5][lr]=av1.y; As[lk+6][lr]=av1.z; As[lk+7][lr]=av1.w;
    Ws[lk+0][lr]=wv0.x; Ws[lk+1][lr]=wv0.y; Ws[lk+2][lr]=wv0.z; Ws[lk+3][lr]=wv0.w;
    Ws[lk+4][lr]=wv1.x; Ws[lk+5][lr]=wv1.y; Ws[lk+6][lr]=wv1.z; Ws[lk+7][lr]=wv1.w;
    __syncthreads();
#pragma unroll
    for (int kk = 0; kk < 16; ++kk) {
      float a_[8], b_[8];
      *(float4*)&a_[0] = *(const float4*)&As[kk][ty*8];
      *(float4*)&a_[4] = *(const float4*)&As[kk][ty*8+4];
      *(float4*)&b_[0] = *(const float4*)&Ws[kk][tx*8];
      *(float4*)&b_[4] = *(const float4*)&Ws[kk][tx*8+4];
#pragma unroll
      for (int i = 0; i < 8; ++i)
#pragma unroll
        for (int j = 0; j < 8; ++j)
          acc[i][j] = fmaf(a_[i], b_[j], acc[i][j]);
    }
    __syncthreads();
  }

  float4 bv0 = *(const float4*)(bias + col0 + tx*8);
  float4 bv1 = *(const float4*)(bias + col0 + tx*8 + 4);
  float bb[8];
  *(float4*)&bb[0] = bv0; *(float4*)&bb[4] = bv1;
#pragma unroll
  for (int i = 0; i < 8; ++i) {
    float o0[4], o1[4];
#pragma unroll
    for (int j = 0; j < 4; ++j) { o0[j] = acc[i][j] + bb[j]; o1[j] = acc[i][j+4] + bb[j+4]; }
    float* crow = C + (size_t)(row0 + ty*8 + i) * Cc + col0 + tx*8;
    *(float4*)crow       = *(float4*)&o0[0];
    *(float4*)(crow + 4) = *(float4*)&o1[0];
  }
}

// ---------------------------------------------------------------------------
// Fused offset network + bilinear sampling (unchanged from R0).
// ---------------------------------------------------------------------------
__global__ __launch_bounds__(128) void offset_sample(
    const float* __restrict__ Q, const float* __restrict__ hidden,
    const float* __restrict__ dw_w, const float* __restrict__ dw_b,
    const float* __restrict__ ln_w, const float* __restrict__ ln_b,
    const float* __restrict__ pw_w, float* __restrict__ XS)
{
  __shared__ float red[128];
  __shared__ float gxy[2];
  const int site = blockIdx.x;          // (b*G+g)*N + n
  const int n = site % Nn;
  const int bg = site / Nn;
  const int g = bg % Gg;
  const int b = bg / Gg;
  const int h = n / Ww, w = n % Ww;
  const int tid = threadIdx.x;

  float tval = 0.f;
  if (tid < CgC) {
    tval = dw_b[tid];
    const float* wp = dw_w + tid * 9;
    const float* qb = Q + (size_t)b * Nn * Cc + g * CgC + tid;
#pragma unroll
    for (int ky = 0; ky < 3; ++ky) {
      int hhp = h + ky - 1;
      if (hhp < 0 || hhp > Hh - 1) continue;
#pragma unroll
      for (int kx = 0; kx < 3; ++kx) {
        int wwp = w + kx - 1;
        if (wwp < 0 || wwp > Ww - 1) continue;
        tval = fmaf(qb[(size_t)(hhp * Ww + wwp) * Cc], wp[ky * 3 + kx], tval);
      }
    }
  }
  red[tid] = (tid < CgC) ? tval : 0.f;
  __syncthreads();
  for (int s = 64; s > 0; s >>= 1) { if (tid < s) red[tid] += red[tid + s]; __syncthreads(); }
  float mu = red[0] * (1.f / 96.f);
  __syncthreads();
  float dv = (tid < CgC) ? (tval - mu) : 0.f;
  red[tid] = dv * dv;
  __syncthreads();
  for (int s = 64; s > 0; s >>= 1) { if (tid < s) red[tid] += red[tid + s]; __syncthreads(); }
  float rstd = rsqrtf(red[0] * (1.f / 96.f) + 1e-5f);
  __syncthreads();

  float a = 0.f;
  if (tid < CgC) {
    float tn = (tval - mu) * rstd * ln_w[tid] + ln_b[tid];
    a = 0.5f * tn * (1.f + erff(tn * 0.70710678118654752f));
  }
  red[tid] = (tid < CgC) ? a * pw_w[tid] : 0.f;
  __syncthreads();
  for (int s = 64; s > 0; s >>= 1) { if (tid < s) red[tid] += red[tid + s]; __syncthreads(); }
  float o0 = red[0];
  __syncthreads();
  red[tid] = (tid < CgC) ? a * pw_w[CgC + tid] : 0.f;
  __syncthreads();
  for (int s = 64; s > 0; s >>= 1) { if (tid < s) red[tid] += red[tid + s]; __syncthreads(); }
  float o1 = red[0];

  if (tid == 0) {
    float offy = tanhf(o0) * (1.f / 13.f);
    float offx = tanhf(o1) * (1.f / 13.f);
    float refy = (h + 0.5f) / 14.f * 2.f - 1.f;
    float refx = (w + 0.5f) / 14.f * 2.f - 1.f;
    float py = offy + refy;
    float px = offx + refx;
    gxy[0] = (px + 1.f) * 0.5f * 13.f;   // gx
    gxy[1] = (py + 1.f) * 0.5f * 13.f;   // gy
  }
  __syncthreads();

  if (tid < CgC) {
    float gx = gxy[0], gy = gxy[1];
    float x0f = floorf(gx), y0f = floorf(gy);
    int x0 = (int)x0f, y0 = (int)y0f;
    float wx1 = gx - x0f, wx0 = 1.f - wx1;
    float wy1 = gy - y0f, wy0 = 1.f - wy1;
    const float* hb = hidden + (size_t)b * Nn * Cc + g * CgC + tid;
    float acc = 0.f;
    if (x0 >= 0 && x0 <= 13 && y0 >= 0 && y0 <= 13)         acc = fmaf(wx0 * wy0, hb[(size_t)(y0 * Ww + x0) * Cc], acc);
    if (x0+1 >= 0 && x0+1 <= 13 && y0 >= 0 && y0 <= 13)     acc = fmaf(wx1 * wy0, hb[(size_t)(y0 * Ww + x0 + 1) * Cc], acc);
    if (x0 >= 0 && x0 <= 13 && y0+1 >= 0 && y0+1 <= 13)     acc = fmaf(wx0 * wy1, hb[(size_t)((y0 + 1) * Ww + x0) * Cc], acc);
    if (x0+1 >= 0 && x0+1 <= 13 && y0+1 >= 0 && y0+1 <= 13) acc = fmaf(wx1 * wy1, hb[(size_t)((y0 + 1) * Ww + x0 + 1) * Cc], acc);
    XS[((size_t)b * Nn + n) * Cc + g * CgC + tid] = acc;
  }
}

// ---------------------------------------------------------------------------
// Scores: one block per (b,h).  Q,K staged transposed [d][m] in LDS (100 KB).
// Each thread computes 8x8 (m x n) tiles over d=0..63; writes RAW scaled S.
// m,n padded to 200 in LDS (pad cols zeroed); 625 tiles over 512 threads.
// ---------------------------------------------------------------------------
__global__ __launch_bounds__(512) void attn_scores_raw(
    const float* __restrict__ Qm, const float* __restrict__ Km,
    float* __restrict__ S)
{
  __shared__ __align__(16) float Qt[64][200];
  __shared__ __align__(16) float Kt[64][200];
  const int tid = threadIdx.x;
  const int hh = blockIdx.x, b = blockIdx.y;
  const float* Qbase = Qm + (size_t)b * Nn * Cc + hh * Dh;
  const float* Kbase = Km + (size_t)b * Nn * Cc + hh * Dh;

  for (int idx = tid; idx < 200 * 64; idx += 512) {
    int mm = idx >> 6, dd = idx & 63;
    float qv = 0.f, kv = 0.f;
    if (mm < Nn) {
      qv = Qbase[(size_t)mm * Cc + dd];
      kv = Kbase[(size_t)mm * Cc + dd];
    }
    Qt[dd][mm] = qv;
    Kt[dd][mm] = kv;
  }
  __syncthreads();

  for (int id = tid; id < 625; id += 512) {
    int tm = id / 25, tn = id - tm * 25;
    float acc[8][8];
#pragma unroll
    for (int i = 0; i < 8; ++i)
#pragma unroll
      for (int j = 0; j < 8; ++j) acc[i][j] = 0.f;
#pragma unroll 4
    for (int dd = 0; dd < 64; ++dd) {
      float q8[8], k8[8];
      *(float4*)&q8[0] = *(const float4*)&Qt[dd][tm * 8];
      *(float4*)&q8[4] = *(const float4*)&Qt[dd][tm * 8 + 4];
      *(float4*)&k8[0] = *(const float4*)&Kt[dd][tn * 8];
      *(float4*)&k8[4] = *(const float4*)&Kt[dd][tn * 8 + 4];
#pragma unroll
      for (int i = 0; i < 8; ++i)
#pragma unroll
        for (int j = 0; j < 8; ++j)
          acc[i][j] = fmaf(q8[i], k8[j], acc[i][j]);
    }
#pragma unroll
    for (int i = 0; i < 8; ++i) {
      int m = tm * 8 + i;
      if (m >= Nn) break;
      float o[8];
#pragma unroll
      for (int j = 0; j < 8; ++j) o[j] = acc[i][j] * 0.125f;
      float* sp = S + (((size_t)b * NHh + hh) * Nn + m) * Nn + tn * 8;
      *(float4*)sp = *(float4*)&o[0];
      if (tn < 24) *(float4*)(sp + 4) = *(float4*)&o[4];
    }
  }
}

// ---------------------------------------------------------------------------
// Softmax + PV: one block (256 thr) per (b,h).
// Per 64-row chunk: stage raw S transposed [n][m] -> row softmax in LDS ->
// write probabilities back to global attn (in place) -> PV with 8x8 tiles,
// 4-way n-split, combine partials through LDS (A_l reused as scratch).
// ---------------------------------------------------------------------------
__global__ __launch_bounds__(256) void attn_softmax_pv(
    float* __restrict__ S, const float* __restrict__ Vm,
    float* __restrict__ OUT)
{
  __shared__ __align__(16) float A_l[196][68];
  __shared__ __align__(16) float V_l[196][64];
  __shared__ float srow[4][64];
  __shared__ float rowmax[64];
  __shared__ float rowinv[64];
  const int tid = threadIdx.x;
  const int hh = blockIdx.x, b = blockIdx.y;

  // stage V  (coalesced; [n][d] conflict-free)
  const float* Vbase = Vm + (size_t)b * Nn * Cc + hh * Dh;
  for (int idx = tid; idx < Nn * Dh; idx += 256) {
    int n = idx >> 6, d = idx & 63;
    V_l[n][d] = Vbase[(size_t)n * Cc + d];
  }

  const int ns  = tid >> 6;          // 0..3  n-split
  const int tmg = (tid >> 3) & 7;    // m-group (8 rows)
  const int tdg = tid & 7;           // d-group (8 dims)
  const int rm  = tid & 63;          // softmax: local row
  const int sg  = tid >> 6;          // softmax: n-segment (49 each)
  float* Sb = S + (((size_t)b * NHh + hh) * Nn) * (size_t)Nn;

  for (int c0 = 0; c0 < Nn; c0 += 64) {
    __syncthreads();   // V ready / previous chunk's scratch reads done
    // stage raw scores chunk, transposed
    for (int e = tid; e < 64 * Nn; e += 256) {
      int ml = e / Nn, n = e - ml * Nn;
      int m = c0 + ml;
      A_l[n][ml] = (m < Nn) ? Sb[(size_t)m * Nn + n] : 0.f;
    }
    __syncthreads();
    // row max
    float mx = -1e30f;
    for (int nn = sg * 49; nn < sg * 49 + 49; ++nn) mx = fmaxf(mx, A_l[nn][rm]);
    srow[sg][rm] = mx;
    __syncthreads();
    if (sg == 0)
      rowmax[rm] = fmaxf(fmaxf(srow[0][rm], srow[1][rm]), fmaxf(srow[2][rm], srow[3][rm]));
    __syncthreads();
    // exp transform (in place) + row sum
    float mrow = rowmax[rm];
    float sm = 0.f;
    for (int nn = sg * 49; nn < sg * 49 + 49; ++nn) {
      float ev = __expf(A_l[nn][rm] - mrow);
      A_l[nn][rm] = ev;
      sm += ev;
    }
    srow[sg][rm] = sm;
    __syncthreads();
    if (sg == 0)
      rowinv[rm] = 1.f / (srow[0][rm] + srow[1][rm] + srow[2][rm] + srow[3][rm]);
    __syncthreads();
    // write probabilities to global attn (in place over raw S)
    for (int e = tid; e < 64 * Nn; e += 256) {
      int ml = e / Nn, n = e - ml * Nn;
      int m = c0 + ml;
      if (m < Nn) Sb[(size_t)m * Nn + n] = A_l[n][ml] * rowinv[ml];
    }
    // PV main loop: acc = sum_n e[n][8m] * V[n][8d]  (1/rowsum folded at store)
    float acc[8][8];
#pragma unroll
    for (int i = 0; i < 8; ++i)
#pragma unroll
      for (int j = 0; j < 8; ++j) acc[i][j] = 0.f;
    for (int n = ns * 49; n < ns * 49 + 49; ++n) {
      float a8[8], v8[8];
      *(float4*)&a8[0] = *(const float4*)&A_l[n][tmg * 8];
      *(float4*)&a8[4] = *(const float4*)&A_l[n][tmg * 8 + 4];
      *(float4*)&v8[0] = *(const float4*)&V_l[n][tdg * 8];
      *(float4*)&v8[4] = *(const float4*)&V_l[n][tdg * 8 + 4];
#pragma unroll
      for (int i = 0; i < 8; ++i)
#pragma unroll
        for (int j = 0; j < 8; ++j)
          acc[i][j] = fmaf(a8[i], v8[j], acc[i][j]);
    }
    __syncthreads();   // A_l reads done -> reuse as reduction scratch
    float* red = &A_l[0][0];   // 16 planes x 192 threads x float4 = 48 KB
    if (ns > 0) {
      int t = (ns - 1) * 64 + tmg * 8 + tdg;
#pragma unroll
      for (int i = 0; i < 8; ++i) {
        *(float4*)&red[((i * 2 + 0) * 192 + t) * 4] = *(float4*)&acc[i][0];
        *(float4*)&red[((i * 2 + 1) * 192 + t) * 4] = *(float4*)&acc[i][4];
      }
    }
    __syncthreads();
    if (ns == 0) {
#pragma unroll
      for (int s = 0; s < 3; ++s) {
        int t = s * 64 + tmg * 8 + tdg;
#pragma unroll
        for (int i = 0; i < 8; ++i) {
          float4 p0 = *(const float4*)&red[((i * 2 + 0) * 192 + t) * 4];
          float4 p1 = *(const float4*)&red[((i * 2 + 1) * 192 + t) * 4];
          acc[i][0] += p0.x; acc[i][1] += p0.y; acc[i][2] += p0.z; acc[i][3] += p0.w;
          acc[i][4] += p1.x; acc[i][5] += p1.y; acc[i][6] += p1.z; acc[i][7] += p1.w;
        }
      }
#pragma unroll
      for (int i = 0; i < 8; ++i) {
        int mlocal = tmg * 8 + i;
        int m = c0 + mlocal;
        if (m < Nn) {
          float iv = rowinv[mlocal];
          float o0[4], o1[4];
#pragma unroll
          for (int j = 0; j < 4; ++j) { o0[j] = acc[i][j] * iv; o1[j] = acc[i][j + 4] * iv; }
          float* op = OUT + ((size_t)b * Nn + m) * Cc + hh * Dh + tdg * 8;
          *(float4*)op       = *(float4*)&o0[0];
          *(float4*)(op + 4) = *(float4*)&o1[0];
        }
      }
    }
  }
}

// ---------------------------------------------------------------------------
extern "C" void kernel_launch(void* const* d_in, const int* in_sizes, int n_in,
                              void* d_out, int out_size, void* d_ws, size_t ws_size,
                              hipStream_t stream) {
  const float* hidden = (const float*)d_in[0];
  const float* Wq = (const float*)d_in[1];
  const float* bq = (const float*)d_in[2];
  const float* dw_w = (const float*)d_in[3];
  const float* dw_b = (const float*)d_in[4];
  const float* ln_w = (const float*)d_in[5];
  const float* ln_b = (const float*)d_in[6];
  const float* pw_w = (const float*)d_in[7];
  const float* Wk = (const float*)d_in[8];
  const float* bk = (const float*)d_in[9];
  const float* Wv = (const float*)d_in[10];
  const float* bv = (const float*)d_in[11];
  const float* Wp = (const float*)d_in[12];
  const float* bp = (const float*)d_in[13];
  const float* Wo = (const float*)d_in[14];
  const float* bo = (const float*)d_in[15];

  const size_t SZ = (size_t)Bsz * Nn * Cc;      // 19,267,584
  float* yout = (float*)d_out;                  // (B,N,C)
  float* attn = yout + SZ;                      // (B,12,196,196) - raw S then probs

  float* Q  = (float*)d_ws;                     // (B,N,C)  later reused as Y1
  float* XS = Q + SZ;                           // (B,N,C)  later reused as OUT
  float* Kb = XS + SZ;
  float* Vb = Kb + SZ;

  dim3 gg(ROWS / 128, Cc / 128);                // (196, 6)

  // 1. Q = hidden @ Wq^T + bq
  gemm_nt_bias<<<gg, 256, 0, stream>>>(hidden, Wq, bq, Q);
  // 2. offset network + bilinear sampling -> XS
  offset_sample<<<Bsz * Gg * Nn, 128, 0, stream>>>(Q, hidden, dw_w, dw_b, ln_w, ln_b, pw_w, XS);
  // 3./4. K,V
  gemm_nt_bias<<<gg, 256, 0, stream>>>(XS, Wk, bk, Kb);
  gemm_nt_bias<<<gg, 256, 0, stream>>>(XS, Wv, bv, Vb);
  // 5. raw scaled scores -> attn region
  attn_scores_raw<<<dim3(NHh, Bsz), 512, 0, stream>>>(Q, Kb, attn);
  // 6. softmax (in-place to probs) + PV -> OUT (reuse XS)
  attn_softmax_pv<<<dim3(NHh, Bsz), 256, 0, stream>>>(attn, Vb, XS);
  // 7. Y1 = OUT @ Wproj^T + bproj (reuse Q)
  gemm_nt_bias<<<gg, 256, 0, stream>>>(XS, Wp, bp, Q);
  // 8. y = Y1 @ Wout^T + bout -> d_out
  gemm_nt_bias<<<gg, 256, 0, stream>>>(Q, Wo, bo, yout);
}

// Round 3
// 1798.483 us; speedup vs baseline: 2.5998x; 1.7518x over previous
//
#include <hip/hip_runtime.h>
#include <math.h>

#define Bsz 128
#define Hh 14
#define Ww 14
#define Nn 196
#define Cc 768
#define Gg 8
#define CgC 96
#define NHh 12
#define Dh 64
#define ROWS (Bsz*Nn)   // 25088

typedef _Float16 half8 __attribute__((ext_vector_type(8)));
typedef float f32x4 __attribute__((ext_vector_type(4)));

// ---------------------------------------------------------------------------
// fp16 MFMA GEMM:  C[r][o] = sum_c A[r][c]*W[o][c] + bias[o]
// A: (25088 x 768) fp32 row-major, W: (768 x 768) fp32 row-major.
// 128x128 tile, BK=64, 256 thr (4 waves, 2x2), mfma_f32_16x16x32_f16.
// fp32->fp16 convert during LDS staging; XOR-swizzled LDS (2-way max = free).
// Block order col-fast: A-panel reused by 6 consecutive blocks (L2-hot),
// W fully L2-resident (2.3 MB).
// ---------------------------------------------------------------------------
__global__ __launch_bounds__(256) void gemm_f16_nt(
    const float* __restrict__ A, const float* __restrict__ W,
    const float* __restrict__ bias, float* __restrict__ C)
{
  __shared__ __align__(16) _Float16 As[128 * 64];
  __shared__ __align__(16) _Float16 Bs[128 * 64];
  const int t = threadIdx.x;
  const int bid = blockIdx.x;
  const int colb = bid % 6, rowb = bid / 6;
  const int row0 = rowb * 128, col0 = colb * 128;
  const int lane = t & 63, w = t >> 6;
  const int wr = w >> 1, wc = w & 1;
  const int l15 = lane & 15, l4 = lane >> 4;

  const int srow = t >> 3;        // 0..31  (staging row within 32-row group)
  const int scol = (t & 7) * 8;   // 0..56  (staging col, 8 elements)
  const int sg   = t & 7;         // staging granule index

  f32x4 acc[4][4];
#pragma unroll
  for (int i = 0; i < 4; ++i)
#pragma unroll
    for (int j = 0; j < 4; ++j) acc[i][j] = (f32x4){0.f, 0.f, 0.f, 0.f};

  for (int kt = 0; kt < 12; ++kt) {
    const int k0 = kt * 64;
    // ---- stage A,W tiles (fp32 -> fp16, swizzled) ----
#pragma unroll
    for (int it = 0; it < 4; ++it) {
      const int r = it * 32 + srow;
      const float* ap = A + (size_t)(row0 + r) * Cc + k0 + scol;
      const float* wp = W + (size_t)(col0 + r) * Cc + k0 + scol;
      float4 a0 = *(const float4*)ap;
      float4 a1 = *(const float4*)(ap + 4);
      float4 w0 = *(const float4*)wp;
      float4 w1 = *(const float4*)(wp + 4);
      half8 ha, hw;
      ha[0] = (_Float16)a0.x; ha[1] = (_Float16)a0.y; ha[2] = (_Float16)a0.z; ha[3] = (_Float16)a0.w;
      ha[4] = (_Float16)a1.x; ha[5] = (_Float16)a1.y; ha[6] = (_Float16)a1.z; ha[7] = (_Float16)a1.w;
      hw[0] = (_Float16)w0.x; hw[1] = (_Float16)w0.y; hw[2] = (_Float16)w0.z; hw[3] = (_Float16)w0.w;
      hw[4] = (_Float16)w1.x; hw[5] = (_Float16)w1.y; hw[6] = (_Float16)w1.z; hw[7] = (_Float16)w1.w;
      const int dst = r * 64 + ((sg ^ (r & 7)) * 8);
      *(half8*)&As[dst] = ha;
      *(half8*)&Bs[dst] = hw;
    }
    __syncthreads();
    // ---- MFMA over BK=64 (two K=32 slices) ----
#pragma unroll
    for (int ks = 0; ks < 2; ++ks) {
      half8 af[4], bf[4];
#pragma unroll
      for (int mi = 0; mi < 4; ++mi) {
        const int r = wr * 64 + mi * 16 + l15;
        const int g = ks * 4 + l4;
        af[mi] = *(const half8*)&As[r * 64 + ((g ^ (r & 7)) * 8)];
      }
#pragma unroll
      for (int ni = 0; ni < 4; ++ni) {
        const int r = wc * 64 + ni * 16 + l15;
        const int g = ks * 4 + l4;
        bf[ni] = *(const half8*)&Bs[r * 64 + ((g ^ (r & 7)) * 8)];
      }
#pragma unroll
      for (int mi = 0; mi < 4; ++mi)
#pragma unroll
        for (int ni = 0; ni < 4; ++ni)
          acc[mi][ni] = __builtin_amdgcn_mfma_f32_16x16x32_f16(af[mi], bf[ni], acc[mi][ni], 0, 0, 0);
    }
    __syncthreads();
  }

  // ---- epilogue: C/D layout col=lane&15, row=(lane>>4)*4+reg ----
#pragma unroll
  for (int ni = 0; ni < 4; ++ni) {
    const int col = col0 + wc * 64 + ni * 16 + l15;
    const float bcol = bias[col];
#pragma unroll
    for (int mi = 0; mi < 4; ++mi) {
      f32x4 v = acc[mi][ni];
      const int rbase = row0 + wr * 64 + mi * 16 + l4 * 4;
#pragma unroll
      for (int r = 0; r < 4; ++r)
        C[(size_t)(rbase + r) * Cc + col] = v[r] + bcol;
    }
  }
}

// ---------------------------------------------------------------------------
// Fused offset network + bilinear sampling (unchanged).
// ---------------------------------------------------------------------------
__global__ __launch_bounds__(128) void offset_sample(
    const float* __restrict__ Q, const float* __restrict__ hidden,
    const float* __restrict__ dw_w, const float* __restrict__ dw_b,
    const float* __restrict__ ln_w, const float* __restrict__ ln_b,
    const float* __restrict__ pw_w, float* __restrict__ XS)
{
  __shared__ float red[128];
  __shared__ float gxy[2];
  const int site = blockIdx.x;          // (b*G+g)*N + n
  const int n = site % Nn;
  const int bg = site / Nn;
  const int g = bg % Gg;
  const int b = bg / Gg;
  const int h = n / Ww, w = n % Ww;
  const int tid = threadIdx.x;

  float tval = 0.f;
  if (tid < CgC) {
    tval = dw_b[tid];
    const float* wp = dw_w + tid * 9;
    const float* qb = Q + (size_t)b * Nn * Cc + g * CgC + tid;
#pragma unroll
    for (int ky = 0; ky < 3; ++ky) {
      int hhp = h + ky - 1;
      if (hhp < 0 || hhp > Hh - 1) continue;
#pragma unroll
      for (int kx = 0; kx < 3; ++kx) {
        int wwp = w + kx - 1;
        if (wwp < 0 || wwp > Ww - 1) continue;
        tval = fmaf(qb[(size_t)(hhp * Ww + wwp) * Cc], wp[ky * 3 + kx], tval);
      }
    }
  }
  red[tid] = (tid < CgC) ? tval : 0.f;
  __syncthreads();
  for (int s = 64; s > 0; s >>= 1) { if (tid < s) red[tid] += red[tid + s]; __syncthreads(); }
  float mu = red[0] * (1.f / 96.f);
  __syncthreads();
  float dv = (tid < CgC) ? (tval - mu) : 0.f;
  red[tid] = dv * dv;
  __syncthreads();
  for (int s = 64; s > 0; s >>= 1) { if (tid < s) red[tid] += red[tid + s]; __syncthreads(); }
  float rstd = rsqrtf(red[0] * (1.f / 96.f) + 1e-5f);
  __syncthreads();

  float a = 0.f;
  if (tid < CgC) {
    float tn = (tval - mu) * rstd * ln_w[tid] + ln_b[tid];
    a = 0.5f * tn * (1.f + erff(tn * 0.70710678118654752f));
  }
  red[tid] = (tid < CgC) ? a * pw_w[tid] : 0.f;
  __syncthreads();
  for (int s = 64; s > 0; s >>= 1) { if (tid < s) red[tid] += red[tid + s]; __syncthreads(); }
  float o0 = red[0];
  __syncthreads();
  red[tid] = (tid < CgC) ? a * pw_w[CgC + tid] : 0.f;
  __syncthreads();
  for (int s = 64; s > 0; s >>= 1) { if (tid < s) red[tid] += red[tid + s]; __syncthreads(); }
  float o1 = red[0];

  if (tid == 0) {
    float offy = tanhf(o0) * (1.f / 13.f);
    float offx = tanhf(o1) * (1.f / 13.f);
    float refy = (h + 0.5f) / 14.f * 2.f - 1.f;
    float refx = (w + 0.5f) / 14.f * 2.f - 1.f;
    float py = offy + refy;
    float px = offx + refx;
    gxy[0] = (px + 1.f) * 0.5f * 13.f;   // gx
    gxy[1] = (py + 1.f) * 0.5f * 13.f;   // gy
  }
  __syncthreads();

  if (tid < CgC) {
    float gx = gxy[0], gy = gxy[1];
    float x0f = floorf(gx), y0f = floorf(gy);
    int x0 = (int)x0f, y0 = (int)y0f;
    float wx1 = gx - x0f, wx0 = 1.f - wx1;
    float wy1 = gy - y0f, wy0 = 1.f - wy1;
    const float* hb = hidden + (size_t)b * Nn * Cc + g * CgC + tid;
    float acc = 0.f;
    if (x0 >= 0 && x0 <= 13 && y0 >= 0 && y0 <= 13)         acc = fmaf(wx0 * wy0, hb[(size_t)(y0 * Ww + x0) * Cc], acc);
    if (x0+1 >= 0 && x0+1 <= 13 && y0 >= 0 && y0 <= 13)     acc = fmaf(wx1 * wy0, hb[(size_t)(y0 * Ww + x0 + 1) * Cc], acc);
    if (x0 >= 0 && x0 <= 13 && y0+1 >= 0 && y0+1 <= 13)     acc = fmaf(wx0 * wy1, hb[(size_t)((y0 + 1) * Ww + x0) * Cc], acc);
    if (x0+1 >= 0 && x0+1 <= 13 && y0+1 >= 0 && y0+1 <= 13) acc = fmaf(wx1 * wy1, hb[(size_t)((y0 + 1) * Ww + x0 + 1) * Cc], acc);
    XS[((size_t)b * Nn + n) * Cc + g * CgC + tid] = acc;
  }
}

// ---------------------------------------------------------------------------
// Scores (unchanged from R1).
// ---------------------------------------------------------------------------
__global__ __launch_bounds__(512) void attn_scores_raw(
    const float* __restrict__ Qm, const float* __restrict__ Km,
    float* __restrict__ S)
{
  __shared__ __align__(16) float Qt[64][200];
  __shared__ __align__(16) float Kt[64][200];
  const int tid = threadIdx.x;
  const int hh = blockIdx.x, b = blockIdx.y;
  const float* Qbase = Qm + (size_t)b * Nn * Cc + hh * Dh;
  const float* Kbase = Km + (size_t)b * Nn * Cc + hh * Dh;

  for (int idx = tid; idx < 200 * 64; idx += 512) {
    int mm = idx >> 6, dd = idx & 63;
    float qv = 0.f, kv = 0.f;
    if (mm < Nn) {
      qv = Qbase[(size_t)mm * Cc + dd];
      kv = Kbase[(size_t)mm * Cc + dd];
    }
    Qt[dd][mm] = qv;
    Kt[dd][mm] = kv;
  }
  __syncthreads();

  for (int id = tid; id < 625; id += 512) {
    int tm = id / 25, tn = id - tm * 25;
    float acc[8][8];
#pragma unroll
    for (int i = 0; i < 8; ++i)
#pragma unroll
      for (int j = 0; j < 8; ++j) acc[i][j] = 0.f;
#pragma unroll 4
    for (int dd = 0; dd < 64; ++dd) {
      float q8[8], k8[8];
      *(float4*)&q8[0] = *(const float4*)&Qt[dd][tm * 8];
      *(float4*)&q8[4] = *(const float4*)&Qt[dd][tm * 8 + 4];
      *(float4*)&k8[0] = *(const float4*)&Kt[dd][tn * 8];
      *(float4*)&k8[4] = *(const float4*)&Kt[dd][tn * 8 + 4];
#pragma unroll
      for (int i = 0; i < 8; ++i)
#pragma unroll
        for (int j = 0; j < 8; ++j)
          acc[i][j] = fmaf(q8[i], k8[j], acc[i][j]);
    }
#pragma unroll
    for (int i = 0; i < 8; ++i) {
      int m = tm * 8 + i;
      if (m >= Nn) break;
      float o[8];
#pragma unroll
      for (int j = 0; j < 8; ++j) o[j] = acc[i][j] * 0.125f;
      float* sp = S + (((size_t)b * NHh + hh) * Nn + m) * Nn + tn * 8;
      *(float4*)sp = *(float4*)&o[0];
      if (tn < 24) *(float4*)(sp + 4) = *(float4*)&o[4];
    }
  }
}

// ---------------------------------------------------------------------------
// Softmax + PV (unchanged from R1).
// ---------------------------------------------------------------------------
__global__ __launch_bounds__(256) void attn_softmax_pv(
    float* __restrict__ S, const float* __restrict__ Vm,
    float* __restrict__ OUT)
{
  __shared__ __align__(16) float A_l[196][68];
  __shared__ __align__(16) float V_l[196][64];
  __shared__ float srow[4][64];
  __shared__ float rowmax[64];
  __shared__ float rowinv[64];
  const int tid = threadIdx.x;
  const int hh = blockIdx.x, b = blockIdx.y;

  const float* Vbase = Vm + (size_t)b * Nn * Cc + hh * Dh;
  for (int idx = tid; idx < Nn * Dh; idx += 256) {
    int n = idx >> 6, d = idx & 63;
    V_l[n][d] = Vbase[(size_t)n * Cc + d];
  }

  const int ns  = tid >> 6;          // 0..3  n-split
  const int tmg = (tid >> 3) & 7;    // m-group (8 rows)
  const int tdg = tid & 7;           // d-group (8 dims)
  const int rm  = tid & 63;          // softmax: local row
  const int sg  = tid >> 6;          // softmax: n-segment (49 each)
  float* Sb = S + (((size_t)b * NHh + hh) * Nn) * (size_t)Nn;

  for (int c0 = 0; c0 < Nn; c0 += 64) {
    __syncthreads();
    for (int e = tid; e < 64 * Nn; e += 256) {
      int ml = e / Nn, n = e - ml * Nn;
      int m = c0 + ml;
      A_l[n][ml] = (m < Nn) ? Sb[(size_t)m * Nn + n] : 0.f;
    }
    __syncthreads();
    float mx = -1e30f;
    for (int nn = sg * 49; nn < sg * 49 + 49; ++nn) mx = fmaxf(mx, A_l[nn][rm]);
    srow[sg][rm] = mx;
    __syncthreads();
    if (sg == 0)
      rowmax[rm] = fmaxf(fmaxf(srow[0][rm], srow[1][rm]), fmaxf(srow[2][rm], srow[3][rm]));
    __syncthreads();
    float mrow = rowmax[rm];
    float sm = 0.f;
    for (int nn = sg * 49; nn < sg * 49 + 49; ++nn) {
      float ev = __expf(A_l[nn][rm] - mrow);
      A_l[nn][rm] = ev;
      sm += ev;
    }
    srow[sg][rm] = sm;
    __syncthreads();
    if (sg == 0)
      rowinv[rm] = 1.f / (srow[0][rm] + srow[1][rm] + srow[2][rm] + srow[3][rm]);
    __syncthreads();
    for (int e = tid; e < 64 * Nn; e += 256) {
      int ml = e / Nn, n = e - ml * Nn;
      int m = c0 + ml;
      if (m < Nn) Sb[(size_t)m * Nn + n] = A_l[n][ml] * rowinv[ml];
    }
    float acc[8][8];
#pragma unroll
    for (int i = 0; i < 8; ++i)
#pragma unroll
      for (int j = 0; j < 8; ++j) acc[i][j] = 0.f;
    for (int n = ns * 49; n < ns * 49 + 49; ++n) {
      float a8[8], v8[8];
      *(float4*)&a8[0] = *(const float4*)&A_l[n][tmg * 8];
      *(float4*)&a8[4] = *(const float4*)&A_l[n][tmg * 8 + 4];
      *(float4*)&v8[0] = *(const float4*)&V_l[n][tdg * 8];
      *(float4*)&v8[4] = *(const float4*)&V_l[n][tdg * 8 + 4];
#pragma unroll
      for (int i = 0; i < 8; ++i)
#pragma unroll
        for (int j = 0; j < 8; ++j)
          acc[i][j] = fmaf(a8[i], v8[j], acc[i][j]);
    }
    __syncthreads();
    float* red = &A_l[0][0];
    if (ns > 0) {
      int tt = (ns - 1) * 64 + tmg * 8 + tdg;
#pragma unroll
      for (int i = 0; i < 8; ++i) {
        *(float4*)&red[((i * 2 + 0) * 192 + tt) * 4] = *(float4*)&acc[i][0];
        *(float4*)&red[((i * 2 + 1) * 192 + tt) * 4] = *(float4*)&acc[i][4];
      }
    }
    __syncthreads();
    if (ns == 0) {
#pragma unroll
      for (int s = 0; s < 3; ++s) {
        int tt = s * 64 + tmg * 8 + tdg;
#pragma unroll
        for (int i = 0; i < 8; ++i) {
          float4 p0 = *(const float4*)&red[((i * 2 + 0) * 192 + tt) * 4];
          float4 p1 = *(const float4*)&red[((i * 2 + 1) * 192 + tt) * 4];
          acc[i][0] += p0.x; acc[i][1] += p0.y; acc[i][2] += p0.z; acc[i][3] += p0.w;
          acc[i][4] += p1.x; acc[i][5] += p1.y; acc[i][6] += p1.z; acc[i][7] += p1.w;
        }
      }
#pragma unroll
      for (int i = 0; i < 8; ++i) {
        int mlocal = tmg * 8 + i;
        int m = c0 + mlocal;
        if (m < Nn) {
          float iv = rowinv[mlocal];
          float o0[4], o1[4];
#pragma unroll
          for (int j = 0; j < 4; ++j) { o0[j] = acc[i][j] * iv; o1[j] = acc[i][j + 4] * iv; }
          float* op = OUT + ((size_t)b * Nn + m) * Cc + hh * Dh + tdg * 8;
          *(float4*)op       = *(float4*)&o0[0];
          *(float4*)(op + 4) = *(float4*)&o1[0];
        }
      }
    }
  }
}

// ---------------------------------------------------------------------------
extern "C" void kernel_launch(void* const* d_in, const int* in_sizes, int n_in,
                              void* d_out, int out_size, void* d_ws, size_t ws_size,
                              hipStream_t stream) {
  const float* hidden = (const float*)d_in[0];
  const float* Wq = (const float*)d_in[1];
  const float* bq = (const float*)d_in[2];
  const float* dw_w = (const float*)d_in[3];
  const float* dw_b = (const float*)d_in[4];
  const float* ln_w = (const float*)d_in[5];
  const float* ln_b = (const float*)d_in[6];
  const float* pw_w = (const float*)d_in[7];
  const float* Wk = (const float*)d_in[8];
  const float* bk = (const float*)d_in[9];
  const float* Wv = (const float*)d_in[10];
  const float* bv = (const float*)d_in[11];
  const float* Wp = (const float*)d_in[12];
  const float* bp = (const float*)d_in[13];
  const float* Wo = (const float*)d_in[14];
  const float* bo = (const float*)d_in[15];

  const size_t SZ = (size_t)Bsz * Nn * Cc;      // 19,267,584
  float* yout = (float*)d_out;                  // (B,N,C)
  float* attn = yout + SZ;                      // (B,12,196,196) - raw S then probs

  float* Q  = (float*)d_ws;                     // (B,N,C)  later reused as Y1
  float* XS = Q + SZ;                           // (B,N,C)  later reused as OUT
  float* Kb = XS + SZ;
  float* Vb = Kb + SZ;

  const int gemm_blocks = (ROWS / 128) * (Cc / 128);  // 196*6 = 1176

  // 1. Q = hidden @ Wq^T + bq
  gemm_f16_nt<<<gemm_blocks, 256, 0, stream>>>(hidden, Wq, bq, Q);
  // 2. offset network + bilinear sampling -> XS
  offset_sample<<<Bsz * Gg * Nn, 128, 0, stream>>>(Q, hidden, dw_w, dw_b, ln_w, ln_b, pw_w, XS);
  // 3./4. K,V
  gemm_f16_nt<<<gemm_blocks, 256, 0, stream>>>(XS, Wk, bk, Kb);
  gemm_f16_nt<<<gemm_blocks, 256, 0, stream>>>(XS, Wv, bv, Vb);
  // 5. raw scaled scores -> attn region
  attn_scores_raw<<<dim3(NHh, Bsz), 512, 0, stream>>>(Q, Kb, attn);
  // 6. softmax (in-place to probs) + PV -> OUT (reuse XS)
  attn_softmax_pv<<<dim3(NHh, Bsz), 256, 0, stream>>>(attn, Vb, XS);
  // 7. Y1 = OUT @ Wproj^T + bproj (reuse Q)
  gemm_f16_nt<<<gemm_blocks, 256, 0, stream>>>(XS, Wp, bp, Q);
  // 8. y = Y1 @ Wout^T + bout -> d_out
  gemm_f16_nt<<<gemm_blocks, 256, 0, stream>>>(Q, Wo, bo, yout);
}

// Round 4
// 1027.419 us; speedup vs baseline: 4.5509x; 1.7505x over previous
//
#include <hip/hip_runtime.h>
#include <math.h>

#define Bsz 128
#define Hh 14
#define Ww 14
#define Nn 196
#define Cc 768
#define Gg 8
#define CgC 96
#define NHh 12
#define Dh 64
#define ROWS (Bsz*Nn)   // 25088

typedef _Float16 half8 __attribute__((ext_vector_type(8)));
typedef float f32x4 __attribute__((ext_vector_type(4)));

// ---------------------------------------------------------------------------
// fp16 MFMA GEMM:  C[r][o] = sum_c A[r][c]*W[o][c] + bias[o]
// 128x128 tile, BK=64, 256 thr (4 waves, 2x2), mfma_f32_16x16x32_f16.
// XCD-chunked bijective blockIdx swizzle (nwg=1176 % 8 == 0).
// ---------------------------------------------------------------------------
__global__ __launch_bounds__(256) void gemm_f16_nt(
    const float* __restrict__ A, const float* __restrict__ W,
    const float* __restrict__ bias, float* __restrict__ C)
{
  __shared__ __align__(16) _Float16 As[128 * 64];
  __shared__ __align__(16) _Float16 Bs[128 * 64];
  const int t = threadIdx.x;
  const int nwg = gridDim.x;
  int bid = blockIdx.x;
  bid = (bid & 7) * (nwg >> 3) + (bid >> 3);   // XCD-chunked, bijective (nwg%8==0)
  const int colb = bid % 6, rowb = bid / 6;
  const int row0 = rowb * 128, col0 = colb * 128;
  const int lane = t & 63, w = t >> 6;
  const int wr = w >> 1, wc = w & 1;
  const int l15 = lane & 15, l4 = lane >> 4;

  const int srow = t >> 3;        // 0..31
  const int scol = (t & 7) * 8;   // 0..56
  const int sg   = t & 7;

  f32x4 acc[4][4];
#pragma unroll
  for (int i = 0; i < 4; ++i)
#pragma unroll
    for (int j = 0; j < 4; ++j) acc[i][j] = (f32x4){0.f, 0.f, 0.f, 0.f};

  for (int kt = 0; kt < 12; ++kt) {
    const int k0 = kt * 64;
#pragma unroll
    for (int it = 0; it < 4; ++it) {
      const int r = it * 32 + srow;
      const float* ap = A + (size_t)(row0 + r) * Cc + k0 + scol;
      const float* wp = W + (size_t)(col0 + r) * Cc + k0 + scol;
      float4 a0 = *(const float4*)ap;
      float4 a1 = *(const float4*)(ap + 4);
      float4 w0 = *(const float4*)wp;
      float4 w1 = *(const float4*)(wp + 4);
      half8 ha, hw;
      ha[0] = (_Float16)a0.x; ha[1] = (_Float16)a0.y; ha[2] = (_Float16)a0.z; ha[3] = (_Float16)a0.w;
      ha[4] = (_Float16)a1.x; ha[5] = (_Float16)a1.y; ha[6] = (_Float16)a1.z; ha[7] = (_Float16)a1.w;
      hw[0] = (_Float16)w0.x; hw[1] = (_Float16)w0.y; hw[2] = (_Float16)w0.z; hw[3] = (_Float16)w0.w;
      hw[4] = (_Float16)w1.x; hw[5] = (_Float16)w1.y; hw[6] = (_Float16)w1.z; hw[7] = (_Float16)w1.w;
      const int dst = r * 64 + ((sg ^ (r & 7)) * 8);
      *(half8*)&As[dst] = ha;
      *(half8*)&Bs[dst] = hw;
    }
    __syncthreads();
#pragma unroll
    for (int ks = 0; ks < 2; ++ks) {
      half8 af[4], bf[4];
#pragma unroll
      for (int mi = 0; mi < 4; ++mi) {
        const int r = wr * 64 + mi * 16 + l15;
        const int g = ks * 4 + l4;
        af[mi] = *(const half8*)&As[r * 64 + ((g ^ (r & 7)) * 8)];
      }
#pragma unroll
      for (int ni = 0; ni < 4; ++ni) {
        const int r = wc * 64 + ni * 16 + l15;
        const int g = ks * 4 + l4;
        bf[ni] = *(const half8*)&Bs[r * 64 + ((g ^ (r & 7)) * 8)];
      }
#pragma unroll
      for (int mi = 0; mi < 4; ++mi)
#pragma unroll
        for (int ni = 0; ni < 4; ++ni)
          acc[mi][ni] = __builtin_amdgcn_mfma_f32_16x16x32_f16(af[mi], bf[ni], acc[mi][ni], 0, 0, 0);
    }
    __syncthreads();
  }

#pragma unroll
  for (int ni = 0; ni < 4; ++ni) {
    const int col = col0 + wc * 64 + ni * 16 + l15;
    const float bcol = bias[col];
#pragma unroll
    for (int mi = 0; mi < 4; ++mi) {
      f32x4 v = acc[mi][ni];
      const int rbase = row0 + wr * 64 + mi * 16 + l4 * 4;
#pragma unroll
      for (int r = 0; r < 4; ++r)
        C[(size_t)(rbase + r) * Cc + col] = v[r] + bcol;
    }
  }
}

// ---------------------------------------------------------------------------
// Fused offset network + bilinear sampling (unchanged).
// ---------------------------------------------------------------------------
__global__ __launch_bounds__(128) void offset_sample(
    const float* __restrict__ Q, const float* __restrict__ hidden,
    const float* __restrict__ dw_w, const float* __restrict__ dw_b,
    const float* __restrict__ ln_w, const float* __restrict__ ln_b,
    const float* __restrict__ pw_w, float* __restrict__ XS)
{
  __shared__ float red[128];
  __shared__ float gxy[2];
  const int site = blockIdx.x;          // (b*G+g)*N + n
  const int n = site % Nn;
  const int bg = site / Nn;
  const int g = bg % Gg;
  const int b = bg / Gg;
  const int h = n / Ww, w = n % Ww;
  const int tid = threadIdx.x;

  float tval = 0.f;
  if (tid < CgC) {
    tval = dw_b[tid];
    const float* wp = dw_w + tid * 9;
    const float* qb = Q + (size_t)b * Nn * Cc + g * CgC + tid;
#pragma unroll
    for (int ky = 0; ky < 3; ++ky) {
      int hhp = h + ky - 1;
      if (hhp < 0 || hhp > Hh - 1) continue;
#pragma unroll
      for (int kx = 0; kx < 3; ++kx) {
        int wwp = w + kx - 1;
        if (wwp < 0 || wwp > Ww - 1) continue;
        tval = fmaf(qb[(size_t)(hhp * Ww + wwp) * Cc], wp[ky * 3 + kx], tval);
      }
    }
  }
  red[tid] = (tid < CgC) ? tval : 0.f;
  __syncthreads();
  for (int s = 64; s > 0; s >>= 1) { if (tid < s) red[tid] += red[tid + s]; __syncthreads(); }
  float mu = red[0] * (1.f / 96.f);
  __syncthreads();
  float dv = (tid < CgC) ? (tval - mu) : 0.f;
  red[tid] = dv * dv;
  __syncthreads();
  for (int s = 64; s > 0; s >>= 1) { if (tid < s) red[tid] += red[tid + s]; __syncthreads(); }
  float rstd = rsqrtf(red[0] * (1.f / 96.f) + 1e-5f);
  __syncthreads();

  float a = 0.f;
  if (tid < CgC) {
    float tn = (tval - mu) * rstd * ln_w[tid] + ln_b[tid];
    a = 0.5f * tn * (1.f + erff(tn * 0.70710678118654752f));
  }
  red[tid] = (tid < CgC) ? a * pw_w[tid] : 0.f;
  __syncthreads();
  for (int s = 64; s > 0; s >>= 1) { if (tid < s) red[tid] += red[tid + s]; __syncthreads(); }
  float o0 = red[0];
  __syncthreads();
  red[tid] = (tid < CgC) ? a * pw_w[CgC + tid] : 0.f;
  __syncthreads();
  for (int s = 64; s > 0; s >>= 1) { if (tid < s) red[tid] += red[tid + s]; __syncthreads(); }
  float o1 = red[0];

  if (tid == 0) {
    float offy = tanhf(o0) * (1.f / 13.f);
    float offx = tanhf(o1) * (1.f / 13.f);
    float refy = (h + 0.5f) / 14.f * 2.f - 1.f;
    float refx = (w + 0.5f) / 14.f * 2.f - 1.f;
    float py = offy + refy;
    float px = offx + refx;
    gxy[0] = (px + 1.f) * 0.5f * 13.f;   // gx
    gxy[1] = (py + 1.f) * 0.5f * 13.f;   // gy
  }
  __syncthreads();

  if (tid < CgC) {
    float gx = gxy[0], gy = gxy[1];
    float x0f = floorf(gx), y0f = floorf(gy);
    int x0 = (int)x0f, y0 = (int)y0f;
    float wx1 = gx - x0f, wx0 = 1.f - wx1;
    float wy1 = gy - y0f, wy0 = 1.f - wy1;
    const float* hb = hidden + (size_t)b * Nn * Cc + g * CgC + tid;
    float acc = 0.f;
    if (x0 >= 0 && x0 <= 13 && y0 >= 0 && y0 <= 13)         acc = fmaf(wx0 * wy0, hb[(size_t)(y0 * Ww + x0) * Cc], acc);
    if (x0+1 >= 0 && x0+1 <= 13 && y0 >= 0 && y0 <= 13)     acc = fmaf(wx1 * wy0, hb[(size_t)(y0 * Ww + x0 + 1) * Cc], acc);
    if (x0 >= 0 && x0 <= 13 && y0+1 >= 0 && y0+1 <= 13)     acc = fmaf(wx0 * wy1, hb[(size_t)((y0 + 1) * Ww + x0) * Cc], acc);
    if (x0+1 >= 0 && x0+1 <= 13 && y0+1 >= 0 && y0+1 <= 13) acc = fmaf(wx1 * wy1, hb[(size_t)((y0 + 1) * Ww + x0 + 1) * Cc], acc);
    XS[((size_t)b * Nn + n) * Cc + g * CgC + tid] = acc;
  }
}

// ---------------------------------------------------------------------------
// Fused attention: one block (4 waves) per (b, h).
// K fp16 [208][72] ([n][k], odd-granule stride: conflict-free column reads),
// V fp16 [64][232] ([d][n], transposed), Sl fp16 [4][16][232] per-wave P.
// Per 16-row m-tile (wave-round-robin over 13 tiles):
//   QK^T via mfma_16x16x32_f16 (Q A-frags direct from global),
//   in-register softmax (4 rows/lane, shfl_xor over 16-lane group),
//   probs -> global attn (fp32) + Sl (fp16), PV via mfma vs transposed V.
// ---------------------------------------------------------------------------
__global__ __launch_bounds__(256) void attn_fused(
    const float* __restrict__ Qm, const float* __restrict__ Km,
    const float* __restrict__ Vm, float* __restrict__ attn,
    float* __restrict__ OUT)
{
  __shared__ __align__(16) _Float16 Kt[208 * 72];
  __shared__ __align__(16) _Float16 Vt[64 * 232];
  __shared__ __align__(16) _Float16 Sl[4][16 * 232];
  const int tid = threadIdx.x;
  const int hh = blockIdx.x, b = blockIdx.y;
  const int lane = tid & 63, wv = tid >> 6;
  const int l15 = lane & 15, l4 = lane >> 4;

  const float* Qbase = Qm + (size_t)b * Nn * Cc + hh * Dh;
  const float* Kbase = Km + (size_t)b * Nn * Cc + hh * Dh;
  const float* Vbase = Vm + (size_t)b * Nn * Cc + hh * Dh;

  // ---- stage K [n][k] fp16, rows 196..207 zero ----
  {
    const int g = tid & 7;
    for (int n = tid >> 3; n < 208; n += 32) {
      half8 hv = {};
      if (n < Nn) {
        const float* p = Kbase + (size_t)n * Cc + g * 8;
        float4 v0 = *(const float4*)p;
        float4 v1 = *(const float4*)(p + 4);
        hv[0] = (_Float16)v0.x; hv[1] = (_Float16)v0.y; hv[2] = (_Float16)v0.z; hv[3] = (_Float16)v0.w;
        hv[4] = (_Float16)v1.x; hv[5] = (_Float16)v1.y; hv[6] = (_Float16)v1.z; hv[7] = (_Float16)v1.w;
      }
      *(half8*)&Kt[n * 72 + g * 8] = hv;
    }
  }
  // ---- stage V transposed [d][n] fp16 ----
  {
    const int d0 = (tid & 15) * 4;
    for (int n = tid >> 4; n < Nn; n += 16) {
      float4 v = *(const float4*)(Vbase + (size_t)n * Cc + d0);
      Vt[(d0 + 0) * 232 + n] = (_Float16)v.x;
      Vt[(d0 + 1) * 232 + n] = (_Float16)v.y;
      Vt[(d0 + 2) * 232 + n] = (_Float16)v.z;
      Vt[(d0 + 3) * 232 + n] = (_Float16)v.w;
    }
    for (int e = tid; e < 64 * 36; e += 256) {
      int d = e / 36, n = Nn + e % 36;
      Vt[d * 232 + n] = (_Float16)0.f;
    }
  }
  // ---- zero Sl pad cols 208..231 (own wave buffer) ----
  for (int e = lane; e < 16 * 24; e += 64) {
    int m = e / 24, c = 208 + e % 24;
    Sl[wv][m * 232 + c] = (_Float16)0.f;
  }
  __syncthreads();

  for (int mt = wv; mt < 13; mt += 4) {
    // Q A-fragments (row = l15, k = l4*8 + j [+32])
    const int qrow = mt * 16 + l15;
    const float* qp = Qbase + (size_t)(qrow < Nn ? qrow : (Nn - 1)) * Cc + l4 * 8;
    float4 q0 = *(const float4*)qp;
    float4 q1 = *(const float4*)(qp + 4);
    float4 q2 = *(const float4*)(qp + 32);
    float4 q3 = *(const float4*)(qp + 36);
    half8 aq0, aq1;
    aq0[0] = (_Float16)q0.x; aq0[1] = (_Float16)q0.y; aq0[2] = (_Float16)q0.z; aq0[3] = (_Float16)q0.w;
    aq0[4] = (_Float16)q1.x; aq0[5] = (_Float16)q1.y; aq0[6] = (_Float16)q1.z; aq0[7] = (_Float16)q1.w;
    aq1[0] = (_Float16)q2.x; aq1[1] = (_Float16)q2.y; aq1[2] = (_Float16)q2.z; aq1[3] = (_Float16)q2.w;
    aq1[4] = (_Float16)q3.x; aq1[5] = (_Float16)q3.y; aq1[6] = (_Float16)q3.z; aq1[7] = (_Float16)q3.w;

    // QK^T: 13 n-tiles x 2 k-slices
    f32x4 accs[13];
#pragma unroll
    for (int nt = 0; nt < 13; ++nt) accs[nt] = (f32x4){0.f, 0.f, 0.f, 0.f};
#pragma unroll
    for (int nt = 0; nt < 13; ++nt) {
      const int rb = (nt * 16 + l15) * 72;
      half8 bk0 = *(const half8*)&Kt[rb + l4 * 8];
      half8 bk1 = *(const half8*)&Kt[rb + 32 + l4 * 8];
      accs[nt] = __builtin_amdgcn_mfma_f32_16x16x32_f16(aq0, bk0, accs[nt], 0, 0, 0);
      accs[nt] = __builtin_amdgcn_mfma_f32_16x16x32_f16(aq1, bk1, accs[nt], 0, 0, 0);
    }

    // scale + mask + row max (rows m = l4*4 + r, cols n = nt*16 + l15)
    float rmax[4] = {-1e30f, -1e30f, -1e30f, -1e30f};
#pragma unroll
    for (int nt = 0; nt < 13; ++nt) {
#pragma unroll
      for (int r = 0; r < 4; ++r) {
        float s = accs[nt][r] * 0.125f;
        if (nt == 12 && l15 >= 4) s = -1e30f;
        accs[nt][r] = s;
        rmax[r] = fmaxf(rmax[r], s);
      }
    }
#pragma unroll
    for (int off = 1; off <= 8; off <<= 1)
#pragma unroll
      for (int r = 0; r < 4; ++r)
        rmax[r] = fmaxf(rmax[r], __shfl_xor(rmax[r], off, 64));

    // exp + row sum
    float rsum[4] = {0.f, 0.f, 0.f, 0.f};
#pragma unroll
    for (int nt = 0; nt < 13; ++nt) {
#pragma unroll
      for (int r = 0; r < 4; ++r) {
        float p = __expf(accs[nt][r] - rmax[r]);
        accs[nt][r] = p;
        rsum[r] += p;
      }
    }
#pragma unroll
    for (int off = 1; off <= 8; off <<= 1)
#pragma unroll
      for (int r = 0; r < 4; ++r)
        rsum[r] += __shfl_xor(rsum[r], off, 64);
    float rinv[4];
#pragma unroll
    for (int r = 0; r < 4; ++r) rinv[r] = 1.f / rsum[r];

    // normalized probs -> Sl (fp16) + global attn (fp32)
    float* ab = attn + (((size_t)b * NHh + hh) * Nn) * (size_t)Nn;
#pragma unroll
    for (int nt = 0; nt < 13; ++nt) {
      const int n = nt * 16 + l15;
#pragma unroll
      for (int r = 0; r < 4; ++r) {
        float pr = accs[nt][r] * rinv[r];
        Sl[wv][(l4 * 4 + r) * 232 + n] = (_Float16)pr;
        const int m = mt * 16 + l4 * 4 + r;
        if (m < Nn && n < Nn) ab[(size_t)m * Nn + n] = pr;
      }
    }

    // PV: A = Sl (row=l15, k=n), B = Vt (row=d, k=n); 7 k-slices of 32
    f32x4 acco[4];
#pragma unroll
    for (int dt = 0; dt < 4; ++dt) acco[dt] = (f32x4){0.f, 0.f, 0.f, 0.f};
#pragma unroll
    for (int nsl = 0; nsl < 7; ++nsl) {
      half8 ap = *(const half8*)&Sl[wv][l15 * 232 + nsl * 32 + l4 * 8];
#pragma unroll
      for (int dt = 0; dt < 4; ++dt) {
        half8 bv = *(const half8*)&Vt[(dt * 16 + l15) * 232 + nsl * 32 + l4 * 8];
        acco[dt] = __builtin_amdgcn_mfma_f32_16x16x32_f16(ap, bv, acco[dt], 0, 0, 0);
      }
    }
#pragma unroll
    for (int dt = 0; dt < 4; ++dt) {
#pragma unroll
      for (int r = 0; r < 4; ++r) {
        const int m = mt * 16 + l4 * 4 + r;
        if (m < Nn)
          OUT[((size_t)b * Nn + m) * Cc + hh * Dh + dt * 16 + l15] = acco[dt][r];
      }
    }
  }
}

// ---------------------------------------------------------------------------
extern "C" void kernel_launch(void* const* d_in, const int* in_sizes, int n_in,
                              void* d_out, int out_size, void* d_ws, size_t ws_size,
                              hipStream_t stream) {
  const float* hidden = (const float*)d_in[0];
  const float* Wq = (const float*)d_in[1];
  const float* bq = (const float*)d_in[2];
  const float* dw_w = (const float*)d_in[3];
  const float* dw_b = (const float*)d_in[4];
  const float* ln_w = (const float*)d_in[5];
  const float* ln_b = (const float*)d_in[6];
  const float* pw_w = (const float*)d_in[7];
  const float* Wk = (const float*)d_in[8];
  const float* bk = (const float*)d_in[9];
  const float* Wv = (const float*)d_in[10];
  const float* bv = (const float*)d_in[11];
  const float* Wp = (const float*)d_in[12];
  const float* bp = (const float*)d_in[13];
  const float* Wo = (const float*)d_in[14];
  const float* bo = (const float*)d_in[15];

  const size_t SZ = (size_t)Bsz * Nn * Cc;      // 19,267,584
  float* yout = (float*)d_out;                  // (B,N,C)
  float* attn = yout + SZ;                      // (B,12,196,196) probs

  float* Q  = (float*)d_ws;                     // (B,N,C)  later reused as Y1
  float* XS = Q + SZ;                           // (B,N,C)  later reused as OUT
  float* Kb = XS + SZ;
  float* Vb = Kb + SZ;

  const int gemm_blocks = (ROWS / 128) * (Cc / 128);  // 1176

  // 1. Q = hidden @ Wq^T + bq
  gemm_f16_nt<<<gemm_blocks, 256, 0, stream>>>(hidden, Wq, bq, Q);
  // 2. offset network + bilinear sampling -> XS
  offset_sample<<<Bsz * Gg * Nn, 128, 0, stream>>>(Q, hidden, dw_w, dw_b, ln_w, ln_b, pw_w, XS);
  // 3./4. K,V
  gemm_f16_nt<<<gemm_blocks, 256, 0, stream>>>(XS, Wk, bk, Kb);
  gemm_f16_nt<<<gemm_blocks, 256, 0, stream>>>(XS, Wv, bv, Vb);
  // 5. fused scores+softmax+PV -> attn (probs) + OUT (reuse XS)
  attn_fused<<<dim3(NHh, Bsz), 256, 0, stream>>>(Q, Kb, Vb, attn, XS);
  // 6. Y1 = OUT @ Wproj^T + bproj (reuse Q)
  gemm_f16_nt<<<gemm_blocks, 256, 0, stream>>>(XS, Wp, bp, Q);
  // 7. y = Y1 @ Wout^T + bout -> d_out
  gemm_f16_nt<<<gemm_blocks, 256, 0, stream>>>(Q, Wo, bo, yout);
}

// Round 5
// 896.666 us; speedup vs baseline: 5.2145x; 1.1458x over previous
//
#include <hip/hip_runtime.h>
#include <math.h>

#define Bsz 128
#define Hh 14
#define Ww 14
#define Nn 196
#define Cc 768
#define Gg 8
#define CgC 96
#define NHh 12
#define Dh 64
#define ROWS (Bsz*Nn)   // 25088

typedef _Float16 half8 __attribute__((ext_vector_type(8)));
typedef float f32x4 __attribute__((ext_vector_type(4)));

// ---------------------------------------------------------------------------
// fp16 MFMA GEMM:  C[r][o] = sum_c A[r][c]*W[o][c] + bias[o]
// 128x128 tile, BK=64, 256 thr (4 waves, 2x2), mfma_f32_16x16x32_f16.
// XCD-chunked bijective blockIdx swizzle (nwg=1176 % 8 == 0).
// ---------------------------------------------------------------------------
__global__ __launch_bounds__(256) void gemm_f16_nt(
    const float* __restrict__ A, const float* __restrict__ W,
    const float* __restrict__ bias, float* __restrict__ C)
{
  __shared__ __align__(16) _Float16 As[128 * 64];
  __shared__ __align__(16) _Float16 Bs[128 * 64];
  const int t = threadIdx.x;
  const int nwg = gridDim.x;
  int bid = blockIdx.x;
  bid = (bid & 7) * (nwg >> 3) + (bid >> 3);   // XCD-chunked, bijective (nwg%8==0)
  const int colb = bid % 6, rowb = bid / 6;
  const int row0 = rowb * 128, col0 = colb * 128;
  const int lane = t & 63, w = t >> 6;
  const int wr = w >> 1, wc = w & 1;
  const int l15 = lane & 15, l4 = lane >> 4;

  const int srow = t >> 3;        // 0..31
  const int scol = (t & 7) * 8;   // 0..56
  const int sg   = t & 7;

  f32x4 acc[4][4];
#pragma unroll
  for (int i = 0; i < 4; ++i)
#pragma unroll
    for (int j = 0; j < 4; ++j) acc[i][j] = (f32x4){0.f, 0.f, 0.f, 0.f};

  for (int kt = 0; kt < 12; ++kt) {
    const int k0 = kt * 64;
#pragma unroll
    for (int it = 0; it < 4; ++it) {
      const int r = it * 32 + srow;
      const float* ap = A + (size_t)(row0 + r) * Cc + k0 + scol;
      const float* wp = W + (size_t)(col0 + r) * Cc + k0 + scol;
      float4 a0 = *(const float4*)ap;
      float4 a1 = *(const float4*)(ap + 4);
      float4 w0 = *(const float4*)wp;
      float4 w1 = *(const float4*)(wp + 4);
      half8 ha, hw;
      ha[0] = (_Float16)a0.x; ha[1] = (_Float16)a0.y; ha[2] = (_Float16)a0.z; ha[3] = (_Float16)a0.w;
      ha[4] = (_Float16)a1.x; ha[5] = (_Float16)a1.y; ha[6] = (_Float16)a1.z; ha[7] = (_Float16)a1.w;
      hw[0] = (_Float16)w0.x; hw[1] = (_Float16)w0.y; hw[2] = (_Float16)w0.z; hw[3] = (_Float16)w0.w;
      hw[4] = (_Float16)w1.x; hw[5] = (_Float16)w1.y; hw[6] = (_Float16)w1.z; hw[7] = (_Float16)w1.w;
      const int dst = r * 64 + ((sg ^ (r & 7)) * 8);
      *(half8*)&As[dst] = ha;
      *(half8*)&Bs[dst] = hw;
    }
    __syncthreads();
#pragma unroll
    for (int ks = 0; ks < 2; ++ks) {
      half8 af[4], bf[4];
#pragma unroll
      for (int mi = 0; mi < 4; ++mi) {
        const int r = wr * 64 + mi * 16 + l15;
        const int g = ks * 4 + l4;
        af[mi] = *(const half8*)&As[r * 64 + ((g ^ (r & 7)) * 8)];
      }
#pragma unroll
      for (int ni = 0; ni < 4; ++ni) {
        const int r = wc * 64 + ni * 16 + l15;
        const int g = ks * 4 + l4;
        bf[ni] = *(const half8*)&Bs[r * 64 + ((g ^ (r & 7)) * 8)];
      }
#pragma unroll
      for (int mi = 0; mi < 4; ++mi)
#pragma unroll
        for (int ni = 0; ni < 4; ++ni)
          acc[mi][ni] = __builtin_amdgcn_mfma_f32_16x16x32_f16(af[mi], bf[ni], acc[mi][ni], 0, 0, 0);
    }
    __syncthreads();
  }

#pragma unroll
  for (int ni = 0; ni < 4; ++ni) {
    const int col = col0 + wc * 64 + ni * 16 + l15;
    const float bcol = bias[col];
#pragma unroll
    for (int mi = 0; mi < 4; ++mi) {
      f32x4 v = acc[mi][ni];
      const int rbase = row0 + wr * 64 + mi * 16 + l4 * 4;
#pragma unroll
      for (int r = 0; r < 4; ++r)
        C[(size_t)(rbase + r) * Cc + col] = v[r] + bcol;
    }
  }
}

// ---------------------------------------------------------------------------
// Offset network + bilinear sampling, restructured: one block per (b,g).
// Q slice and hidden slice (each 196x96 fp32 = 75 KB) staged once in LDS.
// 32-lane group owns one site; lane owns channels {l, l+32, l+64}.
// LN / pointwise reductions: width-32 shfl_xor butterflies (no barriers).
// ---------------------------------------------------------------------------
__global__ __launch_bounds__(256) void offset_sample(
    const float* __restrict__ Q, const float* __restrict__ hidden,
    const float* __restrict__ dw_w, const float* __restrict__ dw_b,
    const float* __restrict__ ln_w, const float* __restrict__ ln_b,
    const float* __restrict__ pw_w, float* __restrict__ XS)
{
  __shared__ float Qs[Nn * CgC];   // 75.3 KB
  __shared__ float Hs[Nn * CgC];   // 75.3 KB
  const int tid = threadIdx.x;
  const int g = blockIdx.x;        // 0..7
  const int b = blockIdx.y;        // 0..127
  const int lane = tid & 63;
  const int cl = tid & 31;         // channel base lane
  const int grp = tid >> 5;        // 0..7  site group

  // ---- stage Q and hidden slices (each element exactly once) ----
  const size_t base = (size_t)b * Nn * Cc + g * CgC;
  for (int i = tid; i < Nn * 24; i += 256) {
    const int n = i / 24, j = i - n * 24;
    const size_t off = base + (size_t)n * Cc + j * 4;
    *(float4*)&Qs[n * CgC + j * 4] = *(const float4*)(Q + off);
    *(float4*)&Hs[n * CgC + j * 4] = *(const float4*)(hidden + off);
  }

  // ---- per-lane weights (channels cl, cl+32, cl+64) ----
  float wdw[3][9], bdw[3], wln[3], bln[3], wp0[3], wp1[3];
#pragma unroll
  for (int k = 0; k < 3; ++k) {
    const int c = cl + k * 32;
#pragma unroll
    for (int t9 = 0; t9 < 9; ++t9) wdw[k][t9] = dw_w[c * 9 + t9];
    bdw[k] = dw_b[c];
    wln[k] = ln_w[c];
    bln[k] = ln_b[c];
    wp0[k] = pw_w[c];
    wp1[k] = pw_w[CgC + c];
  }
  __syncthreads();

  for (int s0 = 0; s0 < Nn; s0 += 8) {
    const int site = s0 + grp;
    if (site >= Nn) break;          // uniform within 32-group
    const int h = site / Ww, w = site % Ww;

    // ---- depthwise 3x3 conv from LDS ----
    float t[3];
#pragma unroll
    for (int k = 0; k < 3; ++k) t[k] = bdw[k];
#pragma unroll
    for (int ky = 0; ky < 3; ++ky) {
      const int hp = h + ky - 1;
      if (hp < 0 || hp > Hh - 1) continue;
#pragma unroll
      for (int kx = 0; kx < 3; ++kx) {
        const int wp = w + kx - 1;
        if (wp < 0 || wp > Ww - 1) continue;
        const float* row = &Qs[(hp * Ww + wp) * CgC + cl];
#pragma unroll
        for (int k = 0; k < 3; ++k)
          t[k] = fmaf(row[k * 32], wdw[k][ky * 3 + kx], t[k]);
      }
    }

    // ---- LN over 96 channels (width-32 butterfly) ----
    float s = t[0] + t[1] + t[2];
#pragma unroll
    for (int off = 1; off <= 16; off <<= 1) s += __shfl_xor(s, off, 32);
    const float mu = s * (1.f / 96.f);
    float d2 = 0.f;
#pragma unroll
    for (int k = 0; k < 3; ++k) { const float d = t[k] - mu; d2 = fmaf(d, d, d2); }
#pragma unroll
    for (int off = 1; off <= 16; off <<= 1) d2 += __shfl_xor(d2, off, 32);
    const float rstd = rsqrtf(d2 * (1.f / 96.f) + 1e-5f);

    // ---- gelu + pointwise -> (o0, o1) ----
    float a[3], p0 = 0.f, p1 = 0.f;
#pragma unroll
    for (int k = 0; k < 3; ++k) {
      const float tn = (t[k] - mu) * rstd * wln[k] + bln[k];
      a[k] = 0.5f * tn * (1.f + erff(tn * 0.70710678118654752f));
      p0 = fmaf(a[k], wp0[k], p0);
      p1 = fmaf(a[k], wp1[k], p1);
    }
#pragma unroll
    for (int off = 1; off <= 16; off <<= 1) {
      p0 += __shfl_xor(p0, off, 32);
      p1 += __shfl_xor(p1, off, 32);
    }

    // ---- grid position ----
    const float offy = tanhf(p0) * (1.f / 13.f);
    const float offx = tanhf(p1) * (1.f / 13.f);
    const float refy = (h + 0.5f) / 14.f * 2.f - 1.f;
    const float refx = (w + 0.5f) / 14.f * 2.f - 1.f;
    const float gx = ((offx + refx) + 1.f) * 0.5f * 13.f;
    const float gy = ((offy + refy) + 1.f) * 0.5f * 13.f;

    // ---- bilinear sample from staged hidden slice ----
    const float x0f = floorf(gx), y0f = floorf(gy);
    const int x0 = (int)x0f, y0 = (int)y0f;
    const float wx1 = gx - x0f, wx0 = 1.f - wx1;
    const float wy1 = gy - y0f, wy0 = 1.f - wy1;
    const bool vx0 = (x0 >= 0) & (x0 <= 13), vx1 = (x0 + 1 >= 0) & (x0 + 1 <= 13);
    const bool vy0 = (y0 >= 0) & (y0 <= 13), vy1 = (y0 + 1 >= 0) & (y0 + 1 <= 13);
    float acc[3] = {0.f, 0.f, 0.f};
#pragma unroll
    for (int k = 0; k < 3; ++k) {
      const int c = cl + k * 32;
      if (vx0 & vy0) acc[k] = fmaf(wx0 * wy0, Hs[(y0 * Ww + x0) * CgC + c], acc[k]);
      if (vx1 & vy0) acc[k] = fmaf(wx1 * wy0, Hs[(y0 * Ww + x0 + 1) * CgC + c], acc[k]);
      if (vx0 & vy1) acc[k] = fmaf(wx0 * wy1, Hs[((y0 + 1) * Ww + x0) * CgC + c], acc[k]);
      if (vx1 & vy1) acc[k] = fmaf(wx1 * wy1, Hs[((y0 + 1) * Ww + x0 + 1) * CgC + c], acc[k]);
    }
    float* xp = XS + ((size_t)b * Nn + site) * Cc + g * CgC + cl;
#pragma unroll
    for (int k = 0; k < 3; ++k) xp[k * 32] = acc[k];
  }
}

// ---------------------------------------------------------------------------
// Fused attention (unchanged from R3): one block (4 waves) per (b, h).
// ---------------------------------------------------------------------------
__global__ __launch_bounds__(256) void attn_fused(
    const float* __restrict__ Qm, const float* __restrict__ Km,
    const float* __restrict__ Vm, float* __restrict__ attn,
    float* __restrict__ OUT)
{
  __shared__ __align__(16) _Float16 Kt[208 * 72];
  __shared__ __align__(16) _Float16 Vt[64 * 232];
  __shared__ __align__(16) _Float16 Sl[4][16 * 232];
  const int tid = threadIdx.x;
  const int hh = blockIdx.x, b = blockIdx.y;
  const int lane = tid & 63, wv = tid >> 6;
  const int l15 = lane & 15, l4 = lane >> 4;

  const float* Qbase = Qm + (size_t)b * Nn * Cc + hh * Dh;
  const float* Kbase = Km + (size_t)b * Nn * Cc + hh * Dh;
  const float* Vbase = Vm + (size_t)b * Nn * Cc + hh * Dh;

  {
    const int g = tid & 7;
    for (int n = tid >> 3; n < 208; n += 32) {
      half8 hv = {};
      if (n < Nn) {
        const float* p = Kbase + (size_t)n * Cc + g * 8;
        float4 v0 = *(const float4*)p;
        float4 v1 = *(const float4*)(p + 4);
        hv[0] = (_Float16)v0.x; hv[1] = (_Float16)v0.y; hv[2] = (_Float16)v0.z; hv[3] = (_Float16)v0.w;
        hv[4] = (_Float16)v1.x; hv[5] = (_Float16)v1.y; hv[6] = (_Float16)v1.z; hv[7] = (_Float16)v1.w;
      }
      *(half8*)&Kt[n * 72 + g * 8] = hv;
    }
  }
  {
    const int d0 = (tid & 15) * 4;
    for (int n = tid >> 4; n < Nn; n += 16) {
      float4 v = *(const float4*)(Vbase + (size_t)n * Cc + d0);
      Vt[(d0 + 0) * 232 + n] = (_Float16)v.x;
      Vt[(d0 + 1) * 232 + n] = (_Float16)v.y;
      Vt[(d0 + 2) * 232 + n] = (_Float16)v.z;
      Vt[(d0 + 3) * 232 + n] = (_Float16)v.w;
    }
    for (int e = tid; e < 64 * 36; e += 256) {
      int d = e / 36, n = Nn + e % 36;
      Vt[d * 232 + n] = (_Float16)0.f;
    }
  }
  for (int e = lane; e < 16 * 24; e += 64) {
    int m = e / 24, c = 208 + e % 24;
    Sl[wv][m * 232 + c] = (_Float16)0.f;
  }
  __syncthreads();

  for (int mt = wv; mt < 13; mt += 4) {
    const int qrow = mt * 16 + l15;
    const float* qp = Qbase + (size_t)(qrow < Nn ? qrow : (Nn - 1)) * Cc + l4 * 8;
    float4 q0 = *(const float4*)qp;
    float4 q1 = *(const float4*)(qp + 4);
    float4 q2 = *(const float4*)(qp + 32);
    float4 q3 = *(const float4*)(qp + 36);
    half8 aq0, aq1;
    aq0[0] = (_Float16)q0.x; aq0[1] = (_Float16)q0.y; aq0[2] = (_Float16)q0.z; aq0[3] = (_Float16)q0.w;
    aq0[4] = (_Float16)q1.x; aq0[5] = (_Float16)q1.y; aq0[6] = (_Float16)q1.z; aq0[7] = (_Float16)q1.w;
    aq1[0] = (_Float16)q2.x; aq1[1] = (_Float16)q2.y; aq1[2] = (_Float16)q2.z; aq1[3] = (_Float16)q2.w;
    aq1[4] = (_Float16)q3.x; aq1[5] = (_Float16)q3.y; aq1[6] = (_Float16)q3.z; aq1[7] = (_Float16)q3.w;

    f32x4 accs[13];
#pragma unroll
    for (int nt = 0; nt < 13; ++nt) accs[nt] = (f32x4){0.f, 0.f, 0.f, 0.f};
#pragma unroll
    for (int nt = 0; nt < 13; ++nt) {
      const int rb = (nt * 16 + l15) * 72;
      half8 bk0 = *(const half8*)&Kt[rb + l4 * 8];
      half8 bk1 = *(const half8*)&Kt[rb + 32 + l4 * 8];
      accs[nt] = __builtin_amdgcn_mfma_f32_16x16x32_f16(aq0, bk0, accs[nt], 0, 0, 0);
      accs[nt] = __builtin_amdgcn_mfma_f32_16x16x32_f16(aq1, bk1, accs[nt], 0, 0, 0);
    }

    float rmax[4] = {-1e30f, -1e30f, -1e30f, -1e30f};
#pragma unroll
    for (int nt = 0; nt < 13; ++nt) {
#pragma unroll
      for (int r = 0; r < 4; ++r) {
        float s = accs[nt][r] * 0.125f;
        if (nt == 12 && l15 >= 4) s = -1e30f;
        accs[nt][r] = s;
        rmax[r] = fmaxf(rmax[r], s);
      }
    }
#pragma unroll
    for (int off = 1; off <= 8; off <<= 1)
#pragma unroll
      for (int r = 0; r < 4; ++r)
        rmax[r] = fmaxf(rmax[r], __shfl_xor(rmax[r], off, 64));

    float rsum[4] = {0.f, 0.f, 0.f, 0.f};
#pragma unroll
    for (int nt = 0; nt < 13; ++nt) {
#pragma unroll
      for (int r = 0; r < 4; ++r) {
        float p = __expf(accs[nt][r] - rmax[r]);
        accs[nt][r] = p;
        rsum[r] += p;
      }
    }
#pragma unroll
    for (int off = 1; off <= 8; off <<= 1)
#pragma unroll
      for (int r = 0; r < 4; ++r)
        rsum[r] += __shfl_xor(rsum[r], off, 64);
    float rinv[4];
#pragma unroll
    for (int r = 0; r < 4; ++r) rinv[r] = 1.f / rsum[r];

    float* ab = attn + (((size_t)b * NHh + hh) * Nn) * (size_t)Nn;
#pragma unroll
    for (int nt = 0; nt < 13; ++nt) {
      const int n = nt * 16 + l15;
#pragma unroll
      for (int r = 0; r < 4; ++r) {
        float pr = accs[nt][r] * rinv[r];
        Sl[wv][(l4 * 4 + r) * 232 + n] = (_Float16)pr;
        const int m = mt * 16 + l4 * 4 + r;
        if (m < Nn && n < Nn) ab[(size_t)m * Nn + n] = pr;
      }
    }

    f32x4 acco[4];
#pragma unroll
    for (int dt = 0; dt < 4; ++dt) acco[dt] = (f32x4){0.f, 0.f, 0.f, 0.f};
#pragma unroll
    for (int nsl = 0; nsl < 7; ++nsl) {
      half8 ap = *(const half8*)&Sl[wv][l15 * 232 + nsl * 32 + l4 * 8];
#pragma unroll
      for (int dt = 0; dt < 4; ++dt) {
        half8 bv = *(const half8*)&Vt[(dt * 16 + l15) * 232 + nsl * 32 + l4 * 8];
        acco[dt] = __builtin_amdgcn_mfma_f32_16x16x32_f16(ap, bv, acco[dt], 0, 0, 0);
      }
    }
#pragma unroll
    for (int dt = 0; dt < 4; ++dt) {
#pragma unroll
      for (int r = 0; r < 4; ++r) {
        const int m = mt * 16 + l4 * 4 + r;
        if (m < Nn)
          OUT[((size_t)b * Nn + m) * Cc + hh * Dh + dt * 16 + l15] = acco[dt][r];
      }
    }
  }
}

// ---------------------------------------------------------------------------
extern "C" void kernel_launch(void* const* d_in, const int* in_sizes, int n_in,
                              void* d_out, int out_size, void* d_ws, size_t ws_size,
                              hipStream_t stream) {
  const float* hidden = (const float*)d_in[0];
  const float* Wq = (const float*)d_in[1];
  const float* bq = (const float*)d_in[2];
  const float* dw_w = (const float*)d_in[3];
  const float* dw_b = (const float*)d_in[4];
  const float* ln_w = (const float*)d_in[5];
  const float* ln_b = (const float*)d_in[6];
  const float* pw_w = (const float*)d_in[7];
  const float* Wk = (const float*)d_in[8];
  const float* bk = (const float*)d_in[9];
  const float* Wv = (const float*)d_in[10];
  const float* bv = (const float*)d_in[11];
  const float* Wp = (const float*)d_in[12];
  const float* bp = (const float*)d_in[13];
  const float* Wo = (const float*)d_in[14];
  const float* bo = (const float*)d_in[15];

  const size_t SZ = (size_t)Bsz * Nn * Cc;      // 19,267,584
  float* yout = (float*)d_out;                  // (B,N,C)
  float* attn = yout + SZ;                      // (B,12,196,196) probs

  float* Q  = (float*)d_ws;                     // (B,N,C)  later reused as Y1
  float* XS = Q + SZ;                           // (B,N,C)  later reused as OUT
  float* Kb = XS + SZ;
  float* Vb = Kb + SZ;

  const int gemm_blocks = (ROWS / 128) * (Cc / 128);  // 1176

  // 1. Q = hidden @ Wq^T + bq
  gemm_f16_nt<<<gemm_blocks, 256, 0, stream>>>(hidden, Wq, bq, Q);
  // 2. offset network + bilinear sampling -> XS  (block per (b,g))
  offset_sample<<<dim3(Gg, Bsz), 256, 0, stream>>>(Q, hidden, dw_w, dw_b, ln_w, ln_b, pw_w, XS);
  // 3./4. K,V
  gemm_f16_nt<<<gemm_blocks, 256, 0, stream>>>(XS, Wk, bk, Kb);
  gemm_f16_nt<<<gemm_blocks, 256, 0, stream>>>(XS, Wv, bv, Vb);
  // 5. fused scores+softmax+PV -> attn (probs) + OUT (reuse XS)
  attn_fused<<<dim3(NHh, Bsz), 256, 0, stream>>>(Q, Kb, Vb, attn, XS);
  // 6. Y1 = OUT @ Wproj^T + bproj (reuse Q)
  gemm_f16_nt<<<gemm_blocks, 256, 0, stream>>>(XS, Wp, bp, Q);
  // 7. y = Y1 @ Wout^T + bout -> d_out
  gemm_f16_nt<<<gemm_blocks, 256, 0, stream>>>(Q, Wo, bo, yout);
}

// Round 6
// 799.923 us; speedup vs baseline: 5.8452x; 1.1209x over previous
//
#include <hip/hip_runtime.h>
#include <math.h>

#define Bsz 128
#define Hh 14
#define Ww 14
#define Nn 196
#define Cc 768
#define Gg 8
#define CgC 96
#define NHh 12
#define Dh 64
#define ROWS (Bsz*Nn)   // 25088

typedef _Float16 half8 __attribute__((ext_vector_type(8)));
typedef float f32x4 __attribute__((ext_vector_type(4)));

// ---------------------------------------------------------------------------
// fp16 MFMA GEMM:  C[r][o] = sum_c A[r][c]*W[o][c] + bias[o]
// 128x128 tile, BK=64, 256 thr (4 waves, 2x2), mfma_f32_16x16x32_f16.
// XCD-chunked bijective blockIdx swizzle (nwg=1176 % 8 == 0).
// ---------------------------------------------------------------------------
__global__ __launch_bounds__(256) void gemm_f16_nt(
    const float* __restrict__ A, const float* __restrict__ W,
    const float* __restrict__ bias, float* __restrict__ C)
{
  __shared__ __align__(16) _Float16 As[128 * 64];
  __shared__ __align__(16) _Float16 Bs[128 * 64];
  const int t = threadIdx.x;
  const int nwg = gridDim.x;
  int bid = blockIdx.x;
  bid = (bid & 7) * (nwg >> 3) + (bid >> 3);   // XCD-chunked, bijective (nwg%8==0)
  const int colb = bid % 6, rowb = bid / 6;
  const int row0 = rowb * 128, col0 = colb * 128;
  const int lane = t & 63, w = t >> 6;
  const int wr = w >> 1, wc = w & 1;
  const int l15 = lane & 15, l4 = lane >> 4;

  const int srow = t >> 3;        // 0..31
  const int scol = (t & 7) * 8;   // 0..56
  const int sg   = t & 7;

  f32x4 acc[4][4];
#pragma unroll
  for (int i = 0; i < 4; ++i)
#pragma unroll
    for (int j = 0; j < 4; ++j) acc[i][j] = (f32x4){0.f, 0.f, 0.f, 0.f};

  for (int kt = 0; kt < 12; ++kt) {
    const int k0 = kt * 64;
#pragma unroll
    for (int it = 0; it < 4; ++it) {
      const int r = it * 32 + srow;
      const float* ap = A + (size_t)(row0 + r) * Cc + k0 + scol;
      const float* wp = W + (size_t)(col0 + r) * Cc + k0 + scol;
      float4 a0 = *(const float4*)ap;
      float4 a1 = *(const float4*)(ap + 4);
      float4 w0 = *(const float4*)wp;
      float4 w1 = *(const float4*)(wp + 4);
      half8 ha, hw;
      ha[0] = (_Float16)a0.x; ha[1] = (_Float16)a0.y; ha[2] = (_Float16)a0.z; ha[3] = (_Float16)a0.w;
      ha[4] = (_Float16)a1.x; ha[5] = (_Float16)a1.y; ha[6] = (_Float16)a1.z; ha[7] = (_Float16)a1.w;
      hw[0] = (_Float16)w0.x; hw[1] = (_Float16)w0.y; hw[2] = (_Float16)w0.z; hw[3] = (_Float16)w0.w;
      hw[4] = (_Float16)w1.x; hw[5] = (_Float16)w1.y; hw[6] = (_Float16)w1.z; hw[7] = (_Float16)w1.w;
      const int dst = r * 64 + ((sg ^ (r & 7)) * 8);
      *(half8*)&As[dst] = ha;
      *(half8*)&Bs[dst] = hw;
    }
    __syncthreads();
#pragma unroll
    for (int ks = 0; ks < 2; ++ks) {
      half8 af[4], bf[4];
#pragma unroll
      for (int mi = 0; mi < 4; ++mi) {
        const int r = wr * 64 + mi * 16 + l15;
        const int g = ks * 4 + l4;
        af[mi] = *(const half8*)&As[r * 64 + ((g ^ (r & 7)) * 8)];
      }
#pragma unroll
      for (int ni = 0; ni < 4; ++ni) {
        const int r = wc * 64 + ni * 16 + l15;
        const int g = ks * 4 + l4;
        bf[ni] = *(const half8*)&Bs[r * 64 + ((g ^ (r & 7)) * 8)];
      }
#pragma unroll
      for (int mi = 0; mi < 4; ++mi)
#pragma unroll
        for (int ni = 0; ni < 4; ++ni)
          acc[mi][ni] = __builtin_amdgcn_mfma_f32_16x16x32_f16(af[mi], bf[ni], acc[mi][ni], 0, 0, 0);
    }
    __syncthreads();
  }

#pragma unroll
  for (int ni = 0; ni < 4; ++ni) {
    const int col = col0 + wc * 64 + ni * 16 + l15;
    const float bcol = bias[col];
#pragma unroll
    for (int mi = 0; mi < 4; ++mi) {
      f32x4 v = acc[mi][ni];
      const int rbase = row0 + wr * 64 + mi * 16 + l4 * 4;
#pragma unroll
      for (int r = 0; r < 4; ++r)
        C[(size_t)(rbase + r) * Cc + col] = v[r] + bcol;
    }
  }
}

// ---------------------------------------------------------------------------
// Offset network + bilinear sampling: one block (512 thr) per (b,g).
// Q slice (196x96 fp32 = 75 KB) staged once in LDS -> 2 blocks/CU.
// __launch_bounds__(512,4) caps VGPR at 128 so 16 waves/CU are resident.
// 16 site-groups of 32 lanes; lane owns channels {cl, cl+32, cl+64}.
// hidden sampled directly from global (per-block slice is L2-hot).
// ---------------------------------------------------------------------------
__global__ __launch_bounds__(512, 4) void offset_sample(
    const float* __restrict__ Q, const float* __restrict__ hidden,
    const float* __restrict__ dw_w, const float* __restrict__ dw_b,
    const float* __restrict__ ln_w, const float* __restrict__ ln_b,
    const float* __restrict__ pw_w, float* __restrict__ XS)
{
  __shared__ float Qs[Nn * CgC];   // 75.3 KB
  const int tid = threadIdx.x;
  const int g = blockIdx.x;        // 0..7
  const int b = blockIdx.y;        // 0..127
  const int cl = tid & 31;         // channel base lane
  const int grp = tid >> 5;        // 0..15  site group

  // ---- stage Q slice (each element exactly once) ----
  const size_t base = (size_t)b * Nn * Cc + g * CgC;
  for (int i = tid; i < Nn * 24; i += 512) {
    const int n = i / 24, j = i - n * 24;
    *(float4*)&Qs[n * CgC + j * 4] = *(const float4*)(Q + base + (size_t)n * Cc + j * 4);
  }

  // ---- per-lane weights (channels cl, cl+32, cl+64) ----
  float wdw[3][9], bdw[3], wln[3], bln[3], wp0[3], wp1[3];
#pragma unroll
  for (int k = 0; k < 3; ++k) {
    const int c = cl + k * 32;
#pragma unroll
    for (int t9 = 0; t9 < 9; ++t9) wdw[k][t9] = dw_w[c * 9 + t9];
    bdw[k] = dw_b[c];
    wln[k] = ln_w[c];
    bln[k] = ln_b[c];
    wp0[k] = pw_w[c];
    wp1[k] = pw_w[CgC + c];
  }
  __syncthreads();

  const float* hb0 = hidden + base;

  for (int s0 = 0; s0 < Nn; s0 += 16) {
    const int site = s0 + grp;
    if (site >= Nn) break;          // uniform within 32-group
    const int h = site / Ww, w = site % Ww;

    // ---- depthwise 3x3 conv from LDS ----
    float t[3];
#pragma unroll
    for (int k = 0; k < 3; ++k) t[k] = bdw[k];
#pragma unroll
    for (int ky = 0; ky < 3; ++ky) {
      const int hp = h + ky - 1;
      if (hp < 0 || hp > Hh - 1) continue;
#pragma unroll
      for (int kx = 0; kx < 3; ++kx) {
        const int wp = w + kx - 1;
        if (wp < 0 || wp > Ww - 1) continue;
        const float* row = &Qs[(hp * Ww + wp) * CgC + cl];
#pragma unroll
        for (int k = 0; k < 3; ++k)
          t[k] = fmaf(row[k * 32], wdw[k][ky * 3 + kx], t[k]);
      }
    }

    // ---- LN over 96 channels (width-32 butterfly) ----
    float s = t[0] + t[1] + t[2];
#pragma unroll
    for (int off = 1; off <= 16; off <<= 1) s += __shfl_xor(s, off, 32);
    const float mu = s * (1.f / 96.f);
    float d2 = 0.f;
#pragma unroll
    for (int k = 0; k < 3; ++k) { const float d = t[k] - mu; d2 = fmaf(d, d, d2); }
#pragma unroll
    for (int off = 1; off <= 16; off <<= 1) d2 += __shfl_xor(d2, off, 32);
    const float rstd = rsqrtf(d2 * (1.f / 96.f) + 1e-5f);

    // ---- gelu + pointwise -> (o0, o1) ----
    float p0 = 0.f, p1 = 0.f;
#pragma unroll
    for (int k = 0; k < 3; ++k) {
      const float tn = (t[k] - mu) * rstd * wln[k] + bln[k];
      const float a = 0.5f * tn * (1.f + erff(tn * 0.70710678118654752f));
      p0 = fmaf(a, wp0[k], p0);
      p1 = fmaf(a, wp1[k], p1);
    }
#pragma unroll
    for (int off = 1; off <= 16; off <<= 1) {
      p0 += __shfl_xor(p0, off, 32);
      p1 += __shfl_xor(p1, off, 32);
    }

    // ---- grid position ----
    const float offy = tanhf(p0) * (1.f / 13.f);
    const float offx = tanhf(p1) * (1.f / 13.f);
    const float refy = (h + 0.5f) / 14.f * 2.f - 1.f;
    const float refx = (w + 0.5f) / 14.f * 2.f - 1.f;
    const float gx = ((offx + refx) + 1.f) * 0.5f * 13.f;
    const float gy = ((offy + refy) + 1.f) * 0.5f * 13.f;

    // ---- bilinear sample of hidden (global, L2-hot slice) ----
    const float x0f = floorf(gx), y0f = floorf(gy);
    const int x0 = (int)x0f, y0 = (int)y0f;
    const float wx1 = gx - x0f, wx0 = 1.f - wx1;
    const float wy1 = gy - y0f, wy0 = 1.f - wy1;
    const bool vx0 = (x0 >= 0) & (x0 <= 13), vx1 = (x0 + 1 >= 0) & (x0 + 1 <= 13);
    const bool vy0 = (y0 >= 0) & (y0 <= 13), vy1 = (y0 + 1 >= 0) & (y0 + 1 <= 13);
    float acc[3] = {0.f, 0.f, 0.f};
#pragma unroll
    for (int k = 0; k < 3; ++k) {
      const int c = cl + k * 32;
      if (vx0 & vy0) acc[k] = fmaf(wx0 * wy0, hb0[(size_t)(y0 * Ww + x0) * Cc + c], acc[k]);
      if (vx1 & vy0) acc[k] = fmaf(wx1 * wy0, hb0[(size_t)(y0 * Ww + x0 + 1) * Cc + c], acc[k]);
      if (vx0 & vy1) acc[k] = fmaf(wx0 * wy1, hb0[(size_t)((y0 + 1) * Ww + x0) * Cc + c], acc[k]);
      if (vx1 & vy1) acc[k] = fmaf(wx1 * wy1, hb0[(size_t)((y0 + 1) * Ww + x0 + 1) * Cc + c], acc[k]);
    }
    float* xp = XS + ((size_t)b * Nn + site) * Cc + g * CgC + cl;
#pragma unroll
    for (int k = 0; k < 3; ++k) xp[k * 32] = acc[k];
  }
}

// ---------------------------------------------------------------------------
// Fused attention (unchanged): one block (4 waves) per (b, h).
// ---------------------------------------------------------------------------
__global__ __launch_bounds__(256) void attn_fused(
    const float* __restrict__ Qm, const float* __restrict__ Km,
    const float* __restrict__ Vm, float* __restrict__ attn,
    float* __restrict__ OUT)
{
  __shared__ __align__(16) _Float16 Kt[208 * 72];
  __shared__ __align__(16) _Float16 Vt[64 * 232];
  __shared__ __align__(16) _Float16 Sl[4][16 * 232];
  const int tid = threadIdx.x;
  const int hh = blockIdx.x, b = blockIdx.y;
  const int lane = tid & 63, wv = tid >> 6;
  const int l15 = lane & 15, l4 = lane >> 4;

  const float* Qbase = Qm + (size_t)b * Nn * Cc + hh * Dh;
  const float* Kbase = Km + (size_t)b * Nn * Cc + hh * Dh;
  const float* Vbase = Vm + (size_t)b * Nn * Cc + hh * Dh;

  {
    const int g = tid & 7;
    for (int n = tid >> 3; n < 208; n += 32) {
      half8 hv = {};
      if (n < Nn) {
        const float* p = Kbase + (size_t)n * Cc + g * 8;
        float4 v0 = *(const float4*)p;
        float4 v1 = *(const float4*)(p + 4);
        hv[0] = (_Float16)v0.x; hv[1] = (_Float16)v0.y; hv[2] = (_Float16)v0.z; hv[3] = (_Float16)v0.w;
        hv[4] = (_Float16)v1.x; hv[5] = (_Float16)v1.y; hv[6] = (_Float16)v1.z; hv[7] = (_Float16)v1.w;
      }
      *(half8*)&Kt[n * 72 + g * 8] = hv;
    }
  }
  {
    const int d0 = (tid & 15) * 4;
    for (int n = tid >> 4; n < Nn; n += 16) {
      float4 v = *(const float4*)(Vbase + (size_t)n * Cc + d0);
      Vt[(d0 + 0) * 232 + n] = (_Float16)v.x;
      Vt[(d0 + 1) * 232 + n] = (_Float16)v.y;
      Vt[(d0 + 2) * 232 + n] = (_Float16)v.z;
      Vt[(d0 + 3) * 232 + n] = (_Float16)v.w;
    }
    for (int e = tid; e < 64 * 36; e += 256) {
      int d = e / 36, n = Nn + e % 36;
      Vt[d * 232 + n] = (_Float16)0.f;
    }
  }
  for (int e = lane; e < 16 * 24; e += 64) {
    int m = e / 24, c = 208 + e % 24;
    Sl[wv][m * 232 + c] = (_Float16)0.f;
  }
  __syncthreads();

  for (int mt = wv; mt < 13; mt += 4) {
    const int qrow = mt * 16 + l15;
    const float* qp = Qbase + (size_t)(qrow < Nn ? qrow : (Nn - 1)) * Cc + l4 * 8;
    float4 q0 = *(const float4*)qp;
    float4 q1 = *(const float4*)(qp + 4);
    float4 q2 = *(const float4*)(qp + 32);
    float4 q3 = *(const float4*)(qp + 36);
    half8 aq0, aq1;
    aq0[0] = (_Float16)q0.x; aq0[1] = (_Float16)q0.y; aq0[2] = (_Float16)q0.z; aq0[3] = (_Float16)q0.w;
    aq0[4] = (_Float16)q1.x; aq0[5] = (_Float16)q1.y; aq0[6] = (_Float16)q1.z; aq0[7] = (_Float16)q1.w;
    aq1[0] = (_Float16)q2.x; aq1[1] = (_Float16)q2.y; aq1[2] = (_Float16)q2.z; aq1[3] = (_Float16)q2.w;
    aq1[4] = (_Float16)q3.x; aq1[5] = (_Float16)q3.y; aq1[6] = (_Float16)q3.z; aq1[7] = (_Float16)q3.w;

    f32x4 accs[13];
#pragma unroll
    for (int nt = 0; nt < 13; ++nt) accs[nt] = (f32x4){0.f, 0.f, 0.f, 0.f};
#pragma unroll
    for (int nt = 0; nt < 13; ++nt) {
      const int rb = (nt * 16 + l15) * 72;
      half8 bk0 = *(const half8*)&Kt[rb + l4 * 8];
      half8 bk1 = *(const half8*)&Kt[rb + 32 + l4 * 8];
      accs[nt] = __builtin_amdgcn_mfma_f32_16x16x32_f16(aq0, bk0, accs[nt], 0, 0, 0);
      accs[nt] = __builtin_amdgcn_mfma_f32_16x16x32_f16(aq1, bk1, accs[nt], 0, 0, 0);
    }

    float rmax[4] = {-1e30f, -1e30f, -1e30f, -1e30f};
#pragma unroll
    for (int nt = 0; nt < 13; ++nt) {
#pragma unroll
      for (int r = 0; r < 4; ++r) {
        float s = accs[nt][r] * 0.125f;
        if (nt == 12 && l15 >= 4) s = -1e30f;
        accs[nt][r] = s;
        rmax[r] = fmaxf(rmax[r], s);
      }
    }
#pragma unroll
    for (int off = 1; off <= 8; off <<= 1)
#pragma unroll
      for (int r = 0; r < 4; ++r)
        rmax[r] = fmaxf(rmax[r], __shfl_xor(rmax[r], off, 64));

    float rsum[4] = {0.f, 0.f, 0.f, 0.f};
#pragma unroll
    for (int nt = 0; nt < 13; ++nt) {
#pragma unroll
      for (int r = 0; r < 4; ++r) {
        float p = __expf(accs[nt][r] - rmax[r]);
        accs[nt][r] = p;
        rsum[r] += p;
      }
    }
#pragma unroll
    for (int off = 1; off <= 8; off <<= 1)
#pragma unroll
      for (int r = 0; r < 4; ++r)
        rsum[r] += __shfl_xor(rsum[r], off, 64);
    float rinv[4];
#pragma unroll
    for (int r = 0; r < 4; ++r) rinv[r] = 1.f / rsum[r];

    float* ab = attn + (((size_t)b * NHh + hh) * Nn) * (size_t)Nn;
#pragma unroll
    for (int nt = 0; nt < 13; ++nt) {
      const int n = nt * 16 + l15;
#pragma unroll
      for (int r = 0; r < 4; ++r) {
        float pr = accs[nt][r] * rinv[r];
        Sl[wv][(l4 * 4 + r) * 232 + n] = (_Float16)pr;
        const int m = mt * 16 + l4 * 4 + r;
        if (m < Nn && n < Nn) ab[(size_t)m * Nn + n] = pr;
      }
    }

    f32x4 acco[4];
#pragma unroll
    for (int dt = 0; dt < 4; ++dt) acco[dt] = (f32x4){0.f, 0.f, 0.f, 0.f};
#pragma unroll
    for (int nsl = 0; nsl < 7; ++nsl) {
      half8 ap = *(const half8*)&Sl[wv][l15 * 232 + nsl * 32 + l4 * 8];
#pragma unroll
      for (int dt = 0; dt < 4; ++dt) {
        half8 bv = *(const half8*)&Vt[(dt * 16 + l15) * 232 + nsl * 32 + l4 * 8];
        acco[dt] = __builtin_amdgcn_mfma_f32_16x16x32_f16(ap, bv, acco[dt], 0, 0, 0);
      }
    }
#pragma unroll
    for (int dt = 0; dt < 4; ++dt) {
#pragma unroll
      for (int r = 0; r < 4; ++r) {
        const int m = mt * 16 + l4 * 4 + r;
        if (m < Nn)
          OUT[((size_t)b * Nn + m) * Cc + hh * Dh + dt * 16 + l15] = acco[dt][r];
      }
    }
  }
}

// ---------------------------------------------------------------------------
extern "C" void kernel_launch(void* const* d_in, const int* in_sizes, int n_in,
                              void* d_out, int out_size, void* d_ws, size_t ws_size,
                              hipStream_t stream) {
  const float* hidden = (const float*)d_in[0];
  const float* Wq = (const float*)d_in[1];
  const float* bq = (const float*)d_in[2];
  const float* dw_w = (const float*)d_in[3];
  const float* dw_b = (const float*)d_in[4];
  const float* ln_w = (const float*)d_in[5];
  const float* ln_b = (const float*)d_in[6];
  const float* pw_w = (const float*)d_in[7];
  const float* Wk = (const float*)d_in[8];
  const float* bk = (const float*)d_in[9];
  const float* Wv = (const float*)d_in[10];
  const float* bv = (const float*)d_in[11];
  const float* Wp = (const float*)d_in[12];
  const float* bp = (const float*)d_in[13];
  const float* Wo = (const float*)d_in[14];
  const float* bo = (const float*)d_in[15];

  const size_t SZ = (size_t)Bsz * Nn * Cc;      // 19,267,584
  float* yout = (float*)d_out;                  // (B,N,C)
  float* attn = yout + SZ;                      // (B,12,196,196) probs

  float* Q  = (float*)d_ws;                     // (B,N,C)  later reused as Y1
  float* XS = Q + SZ;                           // (B,N,C)  later reused as OUT
  float* Kb = XS + SZ;
  float* Vb = Kb + SZ;

  const int gemm_blocks = (ROWS / 128) * (Cc / 128);  // 1176

  // 1. Q = hidden @ Wq^T + bq
  gemm_f16_nt<<<gemm_blocks, 256, 0, stream>>>(hidden, Wq, bq, Q);
  // 2. offset network + bilinear sampling -> XS  (block per (b,g), 512 thr)
  offset_sample<<<dim3(Gg, Bsz), 512, 0, stream>>>(Q, hidden, dw_w, dw_b, ln_w, ln_b, pw_w, XS);
  // 3./4. K,V
  gemm_f16_nt<<<gemm_blocks, 256, 0, stream>>>(XS, Wk, bk, Kb);
  gemm_f16_nt<<<gemm_blocks, 256, 0, stream>>>(XS, Wv, bv, Vb);
  // 5. fused scores+softmax+PV -> attn (probs) + OUT (reuse XS)
  attn_fused<<<dim3(NHh, Bsz), 256, 0, stream>>>(Q, Kb, Vb, attn, XS);
  // 6. Y1 = OUT @ Wproj^T + bproj (reuse Q)
  gemm_f16_nt<<<gemm_blocks, 256, 0, stream>>>(XS, Wp, bp, Q);
  // 7. y = Y1 @ Wout^T + bout -> d_out
  gemm_f16_nt<<<gemm_blocks, 256, 0, stream>>>(Q, Wo, bo, yout);
}

// Round 7
// 569.156 us; speedup vs baseline: 8.2152x; 1.4055x over previous
//
#include <hip/hip_runtime.h>
#include <math.h>

#define Bsz 128
#define Hh 14
#define Ww 14
#define Nn 196
#define Cc 768
#define Gg 8
#define CgC 96
#define NHh 12
#define Dh 64
#define ROWS (Bsz*Nn)   // 25088

typedef _Float16 half8 __attribute__((ext_vector_type(8)));
typedef _Float16 half4 __attribute__((ext_vector_type(4)));
typedef float f32x4 __attribute__((ext_vector_type(4)));

// ---------------------------------------------------------------------------
// fp32 -> fp16 converters (one-shot, memory-bound)
// ---------------------------------------------------------------------------
__global__ __launch_bounds__(256) void cvt_f32_f16(
    const float* __restrict__ src, _Float16* __restrict__ dst, int n8)
{
  const int i = blockIdx.x * 256 + threadIdx.x;
  if (i >= n8) return;
  float4 a = *(const float4*)(src + (size_t)i * 8);
  float4 b = *(const float4*)(src + (size_t)i * 8 + 4);
  half8 h;
  h[0]=(_Float16)a.x; h[1]=(_Float16)a.y; h[2]=(_Float16)a.z; h[3]=(_Float16)a.w;
  h[4]=(_Float16)b.x; h[5]=(_Float16)b.y; h[6]=(_Float16)b.z; h[7]=(_Float16)b.w;
  *(half8*)(dst + (size_t)i * 8) = h;
}

__global__ __launch_bounds__(256) void cvt_w5(
    const float* __restrict__ w0, const float* __restrict__ w1,
    const float* __restrict__ w2, const float* __restrict__ w3,
    const float* __restrict__ w4, _Float16* __restrict__ dst)
{
  const int i = blockIdx.x * 256 + threadIdx.x;   // per 8 elems
  const int per = Cc * Cc / 8;                    // 73728
  if (i >= 5 * per) return;
  const int m = i / per, r = i - m * per;
  const float* s = (m == 0) ? w0 : (m == 1) ? w1 : (m == 2) ? w2 : (m == 3) ? w3 : w4;
  float4 a = *(const float4*)(s + (size_t)r * 8);
  float4 b = *(const float4*)(s + (size_t)r * 8 + 4);
  half8 h;
  h[0]=(_Float16)a.x; h[1]=(_Float16)a.y; h[2]=(_Float16)a.z; h[3]=(_Float16)a.w;
  h[4]=(_Float16)b.x; h[5]=(_Float16)b.y; h[6]=(_Float16)b.z; h[7]=(_Float16)b.w;
  *(half8*)(dst + (size_t)m * Cc * Cc + (size_t)r * 8) = h;
}

// ---------------------------------------------------------------------------
// fp16-in MFMA GEMM:  C[r][o] = sum_c A[r][c]*W[o][c] + bias[o]
// A,W fp16; out fp16 (F16OUT=1) or fp32. 128x128 tile, BK=64, 4 waves.
// Staging: 1 half8 load + 1 ds_write per matrix per 32-row group (no cvt).
// ---------------------------------------------------------------------------
template<int F16OUT>
__global__ __launch_bounds__(256) void gemm_h16(
    const _Float16* __restrict__ A, const _Float16* __restrict__ W,
    const float* __restrict__ bias, void* __restrict__ Cout)
{
  __shared__ __align__(16) _Float16 As[128 * 64];
  __shared__ __align__(16) _Float16 Bs[128 * 64];
  const int t = threadIdx.x;
  const int nwg = gridDim.x;
  int bid = blockIdx.x;
  bid = (bid & 7) * (nwg >> 3) + (bid >> 3);   // XCD-chunked, bijective
  const int colb = bid % 6, rowb = bid / 6;
  const int row0 = rowb * 128, col0 = colb * 128;
  const int lane = t & 63, w = t >> 6;
  const int wr = w >> 1, wc = w & 1;
  const int l15 = lane & 15, l4 = lane >> 4;
  const int srow = t >> 3;        // 0..31
  const int sg   = t & 7;

  f32x4 acc[4][4];
#pragma unroll
  for (int i = 0; i < 4; ++i)
#pragma unroll
    for (int j = 0; j < 4; ++j) acc[i][j] = (f32x4){0.f, 0.f, 0.f, 0.f};

  for (int kt = 0; kt < 12; ++kt) {
    const int k0 = kt * 64;
#pragma unroll
    for (int it = 0; it < 4; ++it) {
      const int r = it * 32 + srow;
      half8 ha = *(const half8*)(A + (size_t)(row0 + r) * Cc + k0 + sg * 8);
      half8 hw = *(const half8*)(W + (size_t)(col0 + r) * Cc + k0 + sg * 8);
      const int dst = r * 64 + ((sg ^ (r & 7)) * 8);
      *(half8*)&As[dst] = ha;
      *(half8*)&Bs[dst] = hw;
    }
    __syncthreads();
#pragma unroll
    for (int ks = 0; ks < 2; ++ks) {
      half8 af[4], bf[4];
#pragma unroll
      for (int mi = 0; mi < 4; ++mi) {
        const int r = wr * 64 + mi * 16 + l15;
        const int g = ks * 4 + l4;
        af[mi] = *(const half8*)&As[r * 64 + ((g ^ (r & 7)) * 8)];
      }
#pragma unroll
      for (int ni = 0; ni < 4; ++ni) {
        const int r = wc * 64 + ni * 16 + l15;
        const int g = ks * 4 + l4;
        bf[ni] = *(const half8*)&Bs[r * 64 + ((g ^ (r & 7)) * 8)];
      }
#pragma unroll
      for (int mi = 0; mi < 4; ++mi)
#pragma unroll
        for (int ni = 0; ni < 4; ++ni)
          acc[mi][ni] = __builtin_amdgcn_mfma_f32_16x16x32_f16(af[mi], bf[ni], acc[mi][ni], 0, 0, 0);
    }
    __syncthreads();
  }

#pragma unroll
  for (int ni = 0; ni < 4; ++ni) {
    const int col = col0 + wc * 64 + ni * 16 + l15;
    const float bcol = bias[col];
#pragma unroll
    for (int mi = 0; mi < 4; ++mi) {
      f32x4 v = acc[mi][ni];
      const int rbase = row0 + wr * 64 + mi * 16 + l4 * 4;
#pragma unroll
      for (int r = 0; r < 4; ++r) {
        if (F16OUT) {
          ((_Float16*)Cout)[(size_t)(rbase + r) * Cc + col] = (_Float16)(v[r] + bcol);
        } else {
          ((float*)Cout)[(size_t)(rbase + r) * Cc + col] = v[r] + bcol;
        }
      }
    }
  }
}

// ---------------------------------------------------------------------------
// Offset network + bilinear sampling: one block (512 thr) per (b,g).
// Q16 slice converted to fp32 LDS; hidden sampled fp32 from global (L2-hot).
// ---------------------------------------------------------------------------
__global__ __launch_bounds__(512, 4) void offset_sample(
    const _Float16* __restrict__ Q16, const float* __restrict__ hidden,
    const float* __restrict__ dw_w, const float* __restrict__ dw_b,
    const float* __restrict__ ln_w, const float* __restrict__ ln_b,
    const float* __restrict__ pw_w, _Float16* __restrict__ XS)
{
  __shared__ float Qs[Nn * CgC];   // 75.3 KB
  const int tid = threadIdx.x;
  const int g = blockIdx.x;        // 0..7
  const int b = blockIdx.y;        // 0..127
  const int cl = tid & 31;         // channel base lane
  const int grp = tid >> 5;        // 0..15  site group

  const size_t base = (size_t)b * Nn * Cc + g * CgC;
  for (int i = tid; i < Nn * 12; i += 512) {
    const int n = i / 12, j = i - n * 12;
    half8 hv = *(const half8*)(Q16 + base + (size_t)n * Cc + j * 8);
#pragma unroll
    for (int e = 0; e < 8; ++e) Qs[n * CgC + j * 8 + e] = (float)hv[e];
  }

  float wdw[3][9], bdw[3], wln[3], bln[3], wp0[3], wp1[3];
#pragma unroll
  for (int k = 0; k < 3; ++k) {
    const int c = cl + k * 32;
#pragma unroll
    for (int t9 = 0; t9 < 9; ++t9) wdw[k][t9] = dw_w[c * 9 + t9];
    bdw[k] = dw_b[c];
    wln[k] = ln_w[c];
    bln[k] = ln_b[c];
    wp0[k] = pw_w[c];
    wp1[k] = pw_w[CgC + c];
  }
  __syncthreads();

  const float* hb0 = hidden + base;

  for (int s0 = 0; s0 < Nn; s0 += 16) {
    const int site = s0 + grp;
    if (site >= Nn) break;
    const int h = site / Ww, w = site % Ww;

    float t[3];
#pragma unroll
    for (int k = 0; k < 3; ++k) t[k] = bdw[k];
#pragma unroll
    for (int ky = 0; ky < 3; ++ky) {
      const int hp = h + ky - 1;
      if (hp < 0 || hp > Hh - 1) continue;
#pragma unroll
      for (int kx = 0; kx < 3; ++kx) {
        const int wp = w + kx - 1;
        if (wp < 0 || wp > Ww - 1) continue;
        const float* row = &Qs[(hp * Ww + wp) * CgC + cl];
#pragma unroll
        for (int k = 0; k < 3; ++k)
          t[k] = fmaf(row[k * 32], wdw[k][ky * 3 + kx], t[k]);
      }
    }

    float s = t[0] + t[1] + t[2];
#pragma unroll
    for (int off = 1; off <= 16; off <<= 1) s += __shfl_xor(s, off, 32);
    const float mu = s * (1.f / 96.f);
    float d2 = 0.f;
#pragma unroll
    for (int k = 0; k < 3; ++k) { const float d = t[k] - mu; d2 = fmaf(d, d, d2); }
#pragma unroll
    for (int off = 1; off <= 16; off <<= 1) d2 += __shfl_xor(d2, off, 32);
    const float rstd = rsqrtf(d2 * (1.f / 96.f) + 1e-5f);

    float p0 = 0.f, p1 = 0.f;
#pragma unroll
    for (int k = 0; k < 3; ++k) {
      const float tn = (t[k] - mu) * rstd * wln[k] + bln[k];
      const float a = 0.5f * tn * (1.f + erff(tn * 0.70710678118654752f));
      p0 = fmaf(a, wp0[k], p0);
      p1 = fmaf(a, wp1[k], p1);
    }
#pragma unroll
    for (int off = 1; off <= 16; off <<= 1) {
      p0 += __shfl_xor(p0, off, 32);
      p1 += __shfl_xor(p1, off, 32);
    }

    const float offy = tanhf(p0) * (1.f / 13.f);
    const float offx = tanhf(p1) * (1.f / 13.f);
    const float refy = (h + 0.5f) / 14.f * 2.f - 1.f;
    const float refx = (w + 0.5f) / 14.f * 2.f - 1.f;
    const float gx = ((offx + refx) + 1.f) * 0.5f * 13.f;
    const float gy = ((offy + refy) + 1.f) * 0.5f * 13.f;

    const float x0f = floorf(gx), y0f = floorf(gy);
    const int x0 = (int)x0f, y0 = (int)y0f;
    const float wx1 = gx - x0f, wx0 = 1.f - wx1;
    const float wy1 = gy - y0f, wy0 = 1.f - wy1;
    const bool vx0 = (x0 >= 0) & (x0 <= 13), vx1 = (x0 + 1 >= 0) & (x0 + 1 <= 13);
    const bool vy0 = (y0 >= 0) & (y0 <= 13), vy1 = (y0 + 1 >= 0) & (y0 + 1 <= 13);
    float acc[3] = {0.f, 0.f, 0.f};
#pragma unroll
    for (int k = 0; k < 3; ++k) {
      const int c = cl + k * 32;
      if (vx0 & vy0) acc[k] = fmaf(wx0 * wy0, hb0[(size_t)(y0 * Ww + x0) * Cc + c], acc[k]);
      if (vx1 & vy0) acc[k] = fmaf(wx1 * wy0, hb0[(size_t)(y0 * Ww + x0 + 1) * Cc + c], acc[k]);
      if (vx0 & vy1) acc[k] = fmaf(wx0 * wy1, hb0[(size_t)((y0 + 1) * Ww + x0) * Cc + c], acc[k]);
      if (vx1 & vy1) acc[k] = fmaf(wx1 * wy1, hb0[(size_t)((y0 + 1) * Ww + x0 + 1) * Cc + c], acc[k]);
    }
    _Float16* xp = XS + ((size_t)b * Nn + site) * Cc + g * CgC + cl;
#pragma unroll
    for (int k = 0; k < 3; ++k) xp[k * 32] = (_Float16)acc[k];
  }
}

// ---------------------------------------------------------------------------
// Fused attention: one block of 8 waves (512 thr) per (b, h), fp16 inputs.
// LDS: Kt 208x72 + Vt 64x232 + Sl[8 waves]x16x232 = 116 KB -> 8 waves/CU.
// ---------------------------------------------------------------------------
__global__ __launch_bounds__(512) void attn_fused(
    const _Float16* __restrict__ Qm, const _Float16* __restrict__ Km,
    const _Float16* __restrict__ Vm, float* __restrict__ attn,
    _Float16* __restrict__ OUT)
{
  __shared__ __align__(16) _Float16 Kt[208 * 72];
  __shared__ __align__(16) _Float16 Vt[64 * 232];
  __shared__ __align__(16) _Float16 Sl[8][16 * 232];
  const int tid = threadIdx.x;
  const int hh = blockIdx.x, b = blockIdx.y;
  const int lane = tid & 63, wv = tid >> 6;     // wv 0..7
  const int l15 = lane & 15, l4 = lane >> 4;

  const _Float16* Qbase = Qm + (size_t)b * Nn * Cc + hh * Dh;
  const _Float16* Kbase = Km + (size_t)b * Nn * Cc + hh * Dh;
  const _Float16* Vbase = Vm + (size_t)b * Nn * Cc + hh * Dh;

  // ---- stage K [n][k], rows 196..207 zero ----
  {
    const int g = tid & 7;
    for (int n = tid >> 3; n < 208; n += 64) {
      half8 hv = {};
      if (n < Nn) hv = *(const half8*)(Kbase + (size_t)n * Cc + g * 8);
      *(half8*)&Kt[n * 72 + g * 8] = hv;
    }
  }
  // ---- stage V transposed [d][n] ----
  {
    const int d0 = (tid & 15) * 4;
    for (int n = tid >> 4; n < Nn; n += 32) {
      half4 v = *(const half4*)(Vbase + (size_t)n * Cc + d0);
      Vt[(d0 + 0) * 232 + n] = v[0];
      Vt[(d0 + 1) * 232 + n] = v[1];
      Vt[(d0 + 2) * 232 + n] = v[2];
      Vt[(d0 + 3) * 232 + n] = v[3];
    }
    for (int e = tid; e < 64 * 36; e += 512) {
      int d = e / 36, n = Nn + e % 36;
      Vt[d * 232 + n] = (_Float16)0.f;
    }
  }
  // ---- zero Sl pad cols 208..231 (own wave buffer) ----
  for (int e = lane; e < 16 * 24; e += 64) {
    int m = e / 24, c = 208 + e % 24;
    Sl[wv][m * 232 + c] = (_Float16)0.f;
  }
  __syncthreads();

  for (int mt = wv; mt < 13; mt += 8) {
    const int qrow = mt * 16 + l15;
    const _Float16* qp = Qbase + (size_t)(qrow < Nn ? qrow : (Nn - 1)) * Cc + l4 * 8;
    half8 aq0 = *(const half8*)qp;
    half8 aq1 = *(const half8*)(qp + 32);

    f32x4 accs[13];
#pragma unroll
    for (int nt = 0; nt < 13; ++nt) accs[nt] = (f32x4){0.f, 0.f, 0.f, 0.f};
#pragma unroll
    for (int nt = 0; nt < 13; ++nt) {
      const int rb = (nt * 16 + l15) * 72;
      half8 bk0 = *(const half8*)&Kt[rb + l4 * 8];
      half8 bk1 = *(const half8*)&Kt[rb + 32 + l4 * 8];
      accs[nt] = __builtin_amdgcn_mfma_f32_16x16x32_f16(aq0, bk0, accs[nt], 0, 0, 0);
      accs[nt] = __builtin_amdgcn_mfma_f32_16x16x32_f16(aq1, bk1, accs[nt], 0, 0, 0);
    }

    float rmax[4] = {-1e30f, -1e30f, -1e30f, -1e30f};
#pragma unroll
    for (int nt = 0; nt < 13; ++nt) {
#pragma unroll
      for (int r = 0; r < 4; ++r) {
        float s = accs[nt][r] * 0.125f;
        if (nt == 12 && l15 >= 4) s = -1e30f;
        accs[nt][r] = s;
        rmax[r] = fmaxf(rmax[r], s);
      }
    }
#pragma unroll
    for (int off = 1; off <= 8; off <<= 1)
#pragma unroll
      for (int r = 0; r < 4; ++r)
        rmax[r] = fmaxf(rmax[r], __shfl_xor(rmax[r], off, 64));

    float rsum[4] = {0.f, 0.f, 0.f, 0.f};
#pragma unroll
    for (int nt = 0; nt < 13; ++nt) {
#pragma unroll
      for (int r = 0; r < 4; ++r) {
        float p = __expf(accs[nt][r] - rmax[r]);
        accs[nt][r] = p;
        rsum[r] += p;
      }
    }
#pragma unroll
    for (int off = 1; off <= 8; off <<= 1)
#pragma unroll
      for (int r = 0; r < 4; ++r)
        rsum[r] += __shfl_xor(rsum[r], off, 64);
    float rinv[4];
#pragma unroll
    for (int r = 0; r < 4; ++r) rinv[r] = 1.f / rsum[r];

    float* ab = attn + (((size_t)b * NHh + hh) * Nn) * (size_t)Nn;
#pragma unroll
    for (int nt = 0; nt < 13; ++nt) {
      const int n = nt * 16 + l15;
#pragma unroll
      for (int r = 0; r < 4; ++r) {
        float pr = accs[nt][r] * rinv[r];
        Sl[wv][(l4 * 4 + r) * 232 + n] = (_Float16)pr;
        const int m = mt * 16 + l4 * 4 + r;
        if (m < Nn && n < Nn) ab[(size_t)m * Nn + n] = pr;
      }
    }

    f32x4 acco[4];
#pragma unroll
    for (int dt = 0; dt < 4; ++dt) acco[dt] = (f32x4){0.f, 0.f, 0.f, 0.f};
#pragma unroll
    for (int nsl = 0; nsl < 7; ++nsl) {
      half8 ap = *(const half8*)&Sl[wv][l15 * 232 + nsl * 32 + l4 * 8];
#pragma unroll
      for (int dt = 0; dt < 4; ++dt) {
        half8 bv = *(const half8*)&Vt[(dt * 16 + l15) * 232 + nsl * 32 + l4 * 8];
        acco[dt] = __builtin_amdgcn_mfma_f32_16x16x32_f16(ap, bv, acco[dt], 0, 0, 0);
      }
    }
#pragma unroll
    for (int dt = 0; dt < 4; ++dt) {
#pragma unroll
      for (int r = 0; r < 4; ++r) {
        const int m = mt * 16 + l4 * 4 + r;
        if (m < Nn)
          OUT[((size_t)b * Nn + m) * Cc + hh * Dh + dt * 16 + l15] = (_Float16)acco[dt][r];
      }
    }
  }
}

// ---------------------------------------------------------------------------
extern "C" void kernel_launch(void* const* d_in, const int* in_sizes, int n_in,
                              void* d_out, int out_size, void* d_ws, size_t ws_size,
                              hipStream_t stream) {
  const float* hidden = (const float*)d_in[0];
  const float* Wq = (const float*)d_in[1];
  const float* bq = (const float*)d_in[2];
  const float* dw_w = (const float*)d_in[3];
  const float* dw_b = (const float*)d_in[4];
  const float* ln_w = (const float*)d_in[5];
  const float* ln_b = (const float*)d_in[6];
  const float* pw_w = (const float*)d_in[7];
  const float* Wk = (const float*)d_in[8];
  const float* bk = (const float*)d_in[9];
  const float* Wv = (const float*)d_in[10];
  const float* bv = (const float*)d_in[11];
  const float* Wp = (const float*)d_in[12];
  const float* bp = (const float*)d_in[13];
  const float* Wo = (const float*)d_in[14];
  const float* bo = (const float*)d_in[15];

  const size_t SZ = (size_t)Bsz * Nn * Cc;      // 19,267,584
  float* yout = (float*)d_out;                  // (B,N,C) fp32
  float* attn = yout + SZ;                      // (B,12,196,196) fp32 probs

  _Float16* h16   = (_Float16*)d_ws;            // fp16 workspace buffers
  _Float16* Q16   = h16   + SZ;
  _Float16* XS16  = Q16   + SZ;
  _Float16* K16   = XS16  + SZ;
  _Float16* V16   = K16   + SZ;
  _Float16* OUT16 = V16   + SZ;
  _Float16* Y116  = OUT16 + SZ;
  _Float16* W16   = Y116  + SZ;                 // 5 x 768 x 768

  const int gemm_blocks = (ROWS / 128) * (Cc / 128);  // 1176
  const int n8 = (int)(SZ / 8);

  // 0. one-shot fp16 conversions
  cvt_f32_f16<<<(n8 + 255) / 256, 256, 0, stream>>>(hidden, h16, n8);
  cvt_w5<<<(5 * Cc * Cc / 8 + 255) / 256, 256, 0, stream>>>(Wq, Wk, Wv, Wp, Wo, W16);

  // 1. Q16 = hidden @ Wq^T + bq
  gemm_h16<1><<<gemm_blocks, 256, 0, stream>>>(h16, W16 + 0 * (size_t)Cc * Cc, bq, Q16);
  // 2. offset network + bilinear sampling -> XS16
  offset_sample<<<dim3(Gg, Bsz), 512, 0, stream>>>(Q16, hidden, dw_w, dw_b, ln_w, ln_b, pw_w, XS16);
  // 3./4. K16, V16
  gemm_h16<1><<<gemm_blocks, 256, 0, stream>>>(XS16, W16 + 1 * (size_t)Cc * Cc, bk, K16);
  gemm_h16<1><<<gemm_blocks, 256, 0, stream>>>(XS16, W16 + 2 * (size_t)Cc * Cc, bv, V16);
  // 5. fused scores+softmax+PV -> attn (fp32 probs) + OUT16
  attn_fused<<<dim3(NHh, Bsz), 512, 0, stream>>>(Q16, K16, V16, attn, OUT16);
  // 6. Y116 = OUT16 @ Wproj^T + bproj
  gemm_h16<1><<<gemm_blocks, 256, 0, stream>>>(OUT16, W16 + 3 * (size_t)Cc * Cc, bp, Y116);
  // 7. y = Y116 @ Wout^T + bout -> d_out (fp32)
  gemm_h16<0><<<gemm_blocks, 256, 0, stream>>>(Y116, W16 + 4 * (size_t)Cc * Cc, bo, yout);
}

// Round 8
// 544.890 us; speedup vs baseline: 8.5810x; 1.0445x over previous
//
#include <hip/hip_runtime.h>
#include <math.h>

#define Bsz 128
#define Hh 14
#define Ww 14
#define Nn 196
#define Cc 768
#define Gg 8
#define CgC 96
#define NHh 12
#define Dh 64
#define ROWS (Bsz*Nn)   // 25088

typedef _Float16 half8 __attribute__((ext_vector_type(8)));
typedef _Float16 half4 __attribute__((ext_vector_type(4)));
typedef float f32x4 __attribute__((ext_vector_type(4)));

// ---------------------------------------------------------------------------
// fp32 -> fp16 converters (one-shot, memory-bound)
// ---------------------------------------------------------------------------
__global__ __launch_bounds__(256) void cvt_f32_f16(
    const float* __restrict__ src, _Float16* __restrict__ dst, int n8)
{
  const int i = blockIdx.x * 256 + threadIdx.x;
  if (i >= n8) return;
  float4 a = *(const float4*)(src + (size_t)i * 8);
  float4 b = *(const float4*)(src + (size_t)i * 8 + 4);
  half8 h;
  h[0]=(_Float16)a.x; h[1]=(_Float16)a.y; h[2]=(_Float16)a.z; h[3]=(_Float16)a.w;
  h[4]=(_Float16)b.x; h[5]=(_Float16)b.y; h[6]=(_Float16)b.z; h[7]=(_Float16)b.w;
  *(half8*)(dst + (size_t)i * 8) = h;
}

__global__ __launch_bounds__(256) void cvt_w5(
    const float* __restrict__ w0, const float* __restrict__ w1,
    const float* __restrict__ w2, const float* __restrict__ w3,
    const float* __restrict__ w4, _Float16* __restrict__ dst)
{
  const int i = blockIdx.x * 256 + threadIdx.x;   // per 8 elems
  const int per = Cc * Cc / 8;                    // 73728
  if (i >= 5 * per) return;
  const int m = i / per, r = i - m * per;
  const float* s = (m == 0) ? w0 : (m == 1) ? w1 : (m == 2) ? w2 : (m == 3) ? w3 : w4;
  float4 a = *(const float4*)(s + (size_t)r * 8);
  float4 b = *(const float4*)(s + (size_t)r * 8 + 4);
  half8 h;
  h[0]=(_Float16)a.x; h[1]=(_Float16)a.y; h[2]=(_Float16)a.z; h[3]=(_Float16)a.w;
  h[4]=(_Float16)b.x; h[5]=(_Float16)b.y; h[6]=(_Float16)b.z; h[7]=(_Float16)b.w;
  *(half8*)(dst + (size_t)m * Cc * Cc + (size_t)r * 8) = h;
}

// ---------------------------------------------------------------------------
// fp16-in MFMA GEMM:  C[r][o] = sum_c A[r][c]*W[o][c] + bias[o]
// 128x128 tile, BK=64, 4 waves. XCD-chunked bijective swizzle.
// ---------------------------------------------------------------------------
template<int F16OUT>
__global__ __launch_bounds__(256) void gemm_h16(
    const _Float16* __restrict__ A, const _Float16* __restrict__ W,
    const float* __restrict__ bias, void* __restrict__ Cout)
{
  __shared__ __align__(16) _Float16 As[128 * 64];
  __shared__ __align__(16) _Float16 Bs[128 * 64];
  const int t = threadIdx.x;
  const int nwg = gridDim.x;
  int bid = blockIdx.x;
  bid = (bid & 7) * (nwg >> 3) + (bid >> 3);
  const int colb = bid % 6, rowb = bid / 6;
  const int row0 = rowb * 128, col0 = colb * 128;
  const int lane = t & 63, w = t >> 6;
  const int wr = w >> 1, wc = w & 1;
  const int l15 = lane & 15, l4 = lane >> 4;
  const int srow = t >> 3;
  const int sg   = t & 7;

  f32x4 acc[4][4];
#pragma unroll
  for (int i = 0; i < 4; ++i)
#pragma unroll
    for (int j = 0; j < 4; ++j) acc[i][j] = (f32x4){0.f, 0.f, 0.f, 0.f};

  for (int kt = 0; kt < 12; ++kt) {
    const int k0 = kt * 64;
#pragma unroll
    for (int it = 0; it < 4; ++it) {
      const int r = it * 32 + srow;
      half8 ha = *(const half8*)(A + (size_t)(row0 + r) * Cc + k0 + sg * 8);
      half8 hw = *(const half8*)(W + (size_t)(col0 + r) * Cc + k0 + sg * 8);
      const int dst = r * 64 + ((sg ^ (r & 7)) * 8);
      *(half8*)&As[dst] = ha;
      *(half8*)&Bs[dst] = hw;
    }
    __syncthreads();
#pragma unroll
    for (int ks = 0; ks < 2; ++ks) {
      half8 af[4], bf[4];
#pragma unroll
      for (int mi = 0; mi < 4; ++mi) {
        const int r = wr * 64 + mi * 16 + l15;
        const int g = ks * 4 + l4;
        af[mi] = *(const half8*)&As[r * 64 + ((g ^ (r & 7)) * 8)];
      }
#pragma unroll
      for (int ni = 0; ni < 4; ++ni) {
        const int r = wc * 64 + ni * 16 + l15;
        const int g = ks * 4 + l4;
        bf[ni] = *(const half8*)&Bs[r * 64 + ((g ^ (r & 7)) * 8)];
      }
#pragma unroll
      for (int mi = 0; mi < 4; ++mi)
#pragma unroll
        for (int ni = 0; ni < 4; ++ni)
          acc[mi][ni] = __builtin_amdgcn_mfma_f32_16x16x32_f16(af[mi], bf[ni], acc[mi][ni], 0, 0, 0);
    }
    __syncthreads();
  }

#pragma unroll
  for (int ni = 0; ni < 4; ++ni) {
    const int col = col0 + wc * 64 + ni * 16 + l15;
    const float bcol = bias[col];
#pragma unroll
    for (int mi = 0; mi < 4; ++mi) {
      f32x4 v = acc[mi][ni];
      const int rbase = row0 + wr * 64 + mi * 16 + l4 * 4;
#pragma unroll
      for (int r = 0; r < 4; ++r) {
        if (F16OUT) {
          ((_Float16*)Cout)[(size_t)(rbase + r) * Cc + col] = (_Float16)(v[r] + bcol);
        } else {
          ((float*)Cout)[(size_t)(rbase + r) * Cc + col] = v[r] + bcol;
        }
      }
    }
  }
}

// ---------------------------------------------------------------------------
// Dual-output K+V GEMM: W = stacked [Wk;Wv] (1536 x 768 fp16).
// Grid 196 x 12 col-tiles; col-tiles 0..5 -> K16, 6..11 -> V16.
// A-panels staged once for both outputs (halves XS16 traffic).
// ---------------------------------------------------------------------------
__global__ __launch_bounds__(256) void gemm_h16_kv(
    const _Float16* __restrict__ A, const _Float16* __restrict__ Wkv,
    const float* __restrict__ bk, const float* __restrict__ bv,
    _Float16* __restrict__ K16, _Float16* __restrict__ V16)
{
  __shared__ __align__(16) _Float16 As[128 * 64];
  __shared__ __align__(16) _Float16 Bs[128 * 64];
  const int t = threadIdx.x;
  const int nwg = gridDim.x;
  int bid = blockIdx.x;
  bid = (bid & 7) * (nwg >> 3) + (bid >> 3);   // nwg = 2352, %8 == 0
  const int colb = bid % 12, rowb = bid / 12;
  const int row0 = rowb * 128, col0 = colb * 128;   // col0 in [0,1536)
  const int lane = t & 63, w = t >> 6;
  const int wr = w >> 1, wc = w & 1;
  const int l15 = lane & 15, l4 = lane >> 4;
  const int srow = t >> 3;
  const int sg   = t & 7;

  _Float16* Cout = (colb < 6) ? K16 : V16;
  const float* bias = (colb < 6) ? bk : bv;
  const int cadj = (colb < 6) ? 0 : Cc;

  f32x4 acc[4][4];
#pragma unroll
  for (int i = 0; i < 4; ++i)
#pragma unroll
    for (int j = 0; j < 4; ++j) acc[i][j] = (f32x4){0.f, 0.f, 0.f, 0.f};

  for (int kt = 0; kt < 12; ++kt) {
    const int k0 = kt * 64;
#pragma unroll
    for (int it = 0; it < 4; ++it) {
      const int r = it * 32 + srow;
      half8 ha = *(const half8*)(A + (size_t)(row0 + r) * Cc + k0 + sg * 8);
      half8 hw = *(const half8*)(Wkv + (size_t)(col0 + r) * Cc + k0 + sg * 8);
      const int dst = r * 64 + ((sg ^ (r & 7)) * 8);
      *(half8*)&As[dst] = ha;
      *(half8*)&Bs[dst] = hw;
    }
    __syncthreads();
#pragma unroll
    for (int ks = 0; ks < 2; ++ks) {
      half8 af[4], bf[4];
#pragma unroll
      for (int mi = 0; mi < 4; ++mi) {
        const int r = wr * 64 + mi * 16 + l15;
        const int g = ks * 4 + l4;
        af[mi] = *(const half8*)&As[r * 64 + ((g ^ (r & 7)) * 8)];
      }
#pragma unroll
      for (int ni = 0; ni < 4; ++ni) {
        const int r = wc * 64 + ni * 16 + l15;
        const int g = ks * 4 + l4;
        bf[ni] = *(const half8*)&Bs[r * 64 + ((g ^ (r & 7)) * 8)];
      }
#pragma unroll
      for (int mi = 0; mi < 4; ++mi)
#pragma unroll
        for (int ni = 0; ni < 4; ++ni)
          acc[mi][ni] = __builtin_amdgcn_mfma_f32_16x16x32_f16(af[mi], bf[ni], acc[mi][ni], 0, 0, 0);
    }
    __syncthreads();
  }

#pragma unroll
  for (int ni = 0; ni < 4; ++ni) {
    const int col = col0 + wc * 64 + ni * 16 + l15;      // 0..1535
    const float bcol = bias[col - cadj];
#pragma unroll
    for (int mi = 0; mi < 4; ++mi) {
      f32x4 v = acc[mi][ni];
      const int rbase = row0 + wr * 64 + mi * 16 + l4 * 4;
#pragma unroll
      for (int r = 0; r < 4; ++r)
        Cout[(size_t)(rbase + r) * Cc + (col - cadj)] = (_Float16)(v[r] + bcol);
    }
  }
}

// ---------------------------------------------------------------------------
// Offset network + bilinear sampling: one block (512 thr) per (b,g).
// ---------------------------------------------------------------------------
__global__ __launch_bounds__(512, 4) void offset_sample(
    const _Float16* __restrict__ Q16, const float* __restrict__ hidden,
    const float* __restrict__ dw_w, const float* __restrict__ dw_b,
    const float* __restrict__ ln_w, const float* __restrict__ ln_b,
    const float* __restrict__ pw_w, _Float16* __restrict__ XS)
{
  __shared__ float Qs[Nn * CgC];   // 75.3 KB
  const int tid = threadIdx.x;
  const int g = blockIdx.x;        // 0..7
  const int b = blockIdx.y;        // 0..127
  const int cl = tid & 31;         // channel base lane
  const int grp = tid >> 5;        // 0..15  site group

  const size_t base = (size_t)b * Nn * Cc + g * CgC;
  for (int i = tid; i < Nn * 12; i += 512) {
    const int n = i / 12, j = i - n * 12;
    half8 hv = *(const half8*)(Q16 + base + (size_t)n * Cc + j * 8);
#pragma unroll
    for (int e = 0; e < 8; ++e) Qs[n * CgC + j * 8 + e] = (float)hv[e];
  }

  float wdw[3][9], bdw[3], wln[3], bln[3], wp0[3], wp1[3];
#pragma unroll
  for (int k = 0; k < 3; ++k) {
    const int c = cl + k * 32;
#pragma unroll
    for (int t9 = 0; t9 < 9; ++t9) wdw[k][t9] = dw_w[c * 9 + t9];
    bdw[k] = dw_b[c];
    wln[k] = ln_w[c];
    bln[k] = ln_b[c];
    wp0[k] = pw_w[c];
    wp1[k] = pw_w[CgC + c];
  }
  __syncthreads();

  const float* hb0 = hidden + base;

  for (int s0 = 0; s0 < Nn; s0 += 16) {
    const int site = s0 + grp;
    if (site >= Nn) break;
    const int h = site / Ww, w = site % Ww;

    float t[3];
#pragma unroll
    for (int k = 0; k < 3; ++k) t[k] = bdw[k];
#pragma unroll
    for (int ky = 0; ky < 3; ++ky) {
      const int hp = h + ky - 1;
      if (hp < 0 || hp > Hh - 1) continue;
#pragma unroll
      for (int kx = 0; kx < 3; ++kx) {
        const int wp = w + kx - 1;
        if (wp < 0 || wp > Ww - 1) continue;
        const float* row = &Qs[(hp * Ww + wp) * CgC + cl];
#pragma unroll
        for (int k = 0; k < 3; ++k)
          t[k] = fmaf(row[k * 32], wdw[k][ky * 3 + kx], t[k]);
      }
    }

    float s = t[0] + t[1] + t[2];
#pragma unroll
    for (int off = 1; off <= 16; off <<= 1) s += __shfl_xor(s, off, 32);
    const float mu = s * (1.f / 96.f);
    float d2 = 0.f;
#pragma unroll
    for (int k = 0; k < 3; ++k) { const float d = t[k] - mu; d2 = fmaf(d, d, d2); }
#pragma unroll
    for (int off = 1; off <= 16; off <<= 1) d2 += __shfl_xor(d2, off, 32);
    const float rstd = rsqrtf(d2 * (1.f / 96.f) + 1e-5f);

    float p0 = 0.f, p1 = 0.f;
#pragma unroll
    for (int k = 0; k < 3; ++k) {
      const float tn = (t[k] - mu) * rstd * wln[k] + bln[k];
      const float a = 0.5f * tn * (1.f + erff(tn * 0.70710678118654752f));
      p0 = fmaf(a, wp0[k], p0);
      p1 = fmaf(a, wp1[k], p1);
    }
#pragma unroll
    for (int off = 1; off <= 16; off <<= 1) {
      p0 += __shfl_xor(p0, off, 32);
      p1 += __shfl_xor(p1, off, 32);
    }

    const float offy = tanhf(p0) * (1.f / 13.f);
    const float offx = tanhf(p1) * (1.f / 13.f);
    const float refy = (h + 0.5f) / 14.f * 2.f - 1.f;
    const float refx = (w + 0.5f) / 14.f * 2.f - 1.f;
    const float gx = ((offx + refx) + 1.f) * 0.5f * 13.f;
    const float gy = ((offy + refy) + 1.f) * 0.5f * 13.f;

    const float x0f = floorf(gx), y0f = floorf(gy);
    const int x0 = (int)x0f, y0 = (int)y0f;
    const float wx1 = gx - x0f, wx0 = 1.f - wx1;
    const float wy1 = gy - y0f, wy0 = 1.f - wy1;
    const bool vx0 = (x0 >= 0) & (x0 <= 13), vx1 = (x0 + 1 >= 0) & (x0 + 1 <= 13);
    const bool vy0 = (y0 >= 0) & (y0 <= 13), vy1 = (y0 + 1 >= 0) & (y0 + 1 <= 13);
    float acc[3] = {0.f, 0.f, 0.f};
#pragma unroll
    for (int k = 0; k < 3; ++k) {
      const int c = cl + k * 32;
      if (vx0 & vy0) acc[k] = fmaf(wx0 * wy0, hb0[(size_t)(y0 * Ww + x0) * Cc + c], acc[k]);
      if (vx1 & vy0) acc[k] = fmaf(wx1 * wy0, hb0[(size_t)(y0 * Ww + x0 + 1) * Cc + c], acc[k]);
      if (vx0 & vy1) acc[k] = fmaf(wx0 * wy1, hb0[(size_t)((y0 + 1) * Ww + x0) * Cc + c], acc[k]);
      if (vx1 & vy1) acc[k] = fmaf(wx1 * wy1, hb0[(size_t)((y0 + 1) * Ww + x0 + 1) * Cc + c], acc[k]);
    }
    _Float16* xp = XS + ((size_t)b * Nn + site) * Cc + g * CgC + cl;
#pragma unroll
    for (int k = 0; k < 3; ++k) xp[k * 32] = (_Float16)acc[k];
  }
}

// ---------------------------------------------------------------------------
// Fused attention: one block of 8 waves (512 thr) per (b, h), fp16 inputs.
// LDS: Kt 208x72 (29.9K) + Vt 64x232 (29.7K) + Ps[8][16][40] (10.2K) = 69.9 KB
//   -> 2 blocks/CU, 16 waves/CU. __launch_bounds__(512,4) caps VGPR at 128.
// Per-wave P transposed through a tiny 16x40 slice buffer inside the PV loop.
// ---------------------------------------------------------------------------
__global__ __launch_bounds__(512, 4) void attn_fused(
    const _Float16* __restrict__ Qm, const _Float16* __restrict__ Km,
    const _Float16* __restrict__ Vm, float* __restrict__ attn,
    _Float16* __restrict__ OUT)
{
  __shared__ __align__(16) _Float16 Kt[208 * 72];
  __shared__ __align__(16) _Float16 Vt[64 * 232];
  __shared__ __align__(16) _Float16 Ps[8][16 * 40];
  const int tid = threadIdx.x;
  const int hh = blockIdx.x, b = blockIdx.y;
  const int lane = tid & 63, wv = tid >> 6;     // wv 0..7
  const int l15 = lane & 15, l4 = lane >> 4;

  const _Float16* Qbase = Qm + (size_t)b * Nn * Cc + hh * Dh;
  const _Float16* Kbase = Km + (size_t)b * Nn * Cc + hh * Dh;
  const _Float16* Vbase = Vm + (size_t)b * Nn * Cc + hh * Dh;

  // ---- stage K [n][k], rows 196..207 zero ----
  {
    const int g = tid & 7;
    for (int n = tid >> 3; n < 208; n += 64) {
      half8 hv = {};
      if (n < Nn) hv = *(const half8*)(Kbase + (size_t)n * Cc + g * 8);
      *(half8*)&Kt[n * 72 + g * 8] = hv;
    }
  }
  // ---- stage V transposed [d][n] ----
  {
    const int d0 = (tid & 15) * 4;
    for (int n = tid >> 4; n < Nn; n += 32) {
      half4 v = *(const half4*)(Vbase + (size_t)n * Cc + d0);
      Vt[(d0 + 0) * 232 + n] = v[0];
      Vt[(d0 + 1) * 232 + n] = v[1];
      Vt[(d0 + 2) * 232 + n] = v[2];
      Vt[(d0 + 3) * 232 + n] = v[3];
    }
    for (int e = tid; e < 64 * 36; e += 512) {
      int d = e / 36, n = Nn + e % 36;
      Vt[d * 232 + n] = (_Float16)0.f;
    }
  }
  __syncthreads();

  for (int mt = wv; mt < 13; mt += 8) {
    const int qrow = mt * 16 + l15;
    const _Float16* qp = Qbase + (size_t)(qrow < Nn ? qrow : (Nn - 1)) * Cc + l4 * 8;
    half8 aq0 = *(const half8*)qp;
    half8 aq1 = *(const half8*)(qp + 32);

    f32x4 accs[13];
#pragma unroll
    for (int nt = 0; nt < 13; ++nt) accs[nt] = (f32x4){0.f, 0.f, 0.f, 0.f};
#pragma unroll
    for (int nt = 0; nt < 13; ++nt) {
      const int rb = (nt * 16 + l15) * 72;
      half8 bk0 = *(const half8*)&Kt[rb + l4 * 8];
      half8 bk1 = *(const half8*)&Kt[rb + 32 + l4 * 8];
      accs[nt] = __builtin_amdgcn_mfma_f32_16x16x32_f16(aq0, bk0, accs[nt], 0, 0, 0);
      accs[nt] = __builtin_amdgcn_mfma_f32_16x16x32_f16(aq1, bk1, accs[nt], 0, 0, 0);
    }

    float rmax[4] = {-1e30f, -1e30f, -1e30f, -1e30f};
#pragma unroll
    for (int nt = 0; nt < 13; ++nt) {
#pragma unroll
      for (int r = 0; r < 4; ++r) {
        float s = accs[nt][r] * 0.125f;
        if (nt == 12 && l15 >= 4) s = -1e30f;
        accs[nt][r] = s;
        rmax[r] = fmaxf(rmax[r], s);
      }
    }
#pragma unroll
    for (int off = 1; off <= 8; off <<= 1)
#pragma unroll
      for (int r = 0; r < 4; ++r)
        rmax[r] = fmaxf(rmax[r], __shfl_xor(rmax[r], off, 64));

    float rsum[4] = {0.f, 0.f, 0.f, 0.f};
#pragma unroll
    for (int nt = 0; nt < 13; ++nt) {
#pragma unroll
      for (int r = 0; r < 4; ++r) {
        float p = __expf(accs[nt][r] - rmax[r]);
        accs[nt][r] = p;
        rsum[r] += p;
      }
    }
#pragma unroll
    for (int off = 1; off <= 8; off <<= 1)
#pragma unroll
      for (int r = 0; r < 4; ++r)
        rsum[r] += __shfl_xor(rsum[r], off, 64);
    float rinv[4];
#pragma unroll
    for (int r = 0; r < 4; ++r) rinv[r] = 1.f / rsum[r];

    // normalize in-register + write global probs (fp32)
    float* ab = attn + (((size_t)b * NHh + hh) * Nn) * (size_t)Nn;
#pragma unroll
    for (int nt = 0; nt < 13; ++nt) {
      const int n = nt * 16 + l15;
#pragma unroll
      for (int r = 0; r < 4; ++r) {
        float pr = accs[nt][r] * rinv[r];
        accs[nt][r] = pr;
        const int m = mt * 16 + l4 * 4 + r;
        if (m < Nn && n < Nn) ab[(size_t)m * Nn + n] = pr;
      }
    }

    // PV: per 32-wide n-slice, transpose P through tiny per-wave LDS buffer
    f32x4 acco[4];
#pragma unroll
    for (int dt = 0; dt < 4; ++dt) acco[dt] = (f32x4){0.f, 0.f, 0.f, 0.f};
#pragma unroll
    for (int nsl = 0; nsl < 7; ++nsl) {
#pragma unroll
      for (int h2 = 0; h2 < 2; ++h2) {
        const int nt = nsl * 2 + h2;
        if (nt < 13) {
#pragma unroll
          for (int r = 0; r < 4; ++r)
            Ps[wv][(l4 * 4 + r) * 40 + h2 * 16 + l15] = (_Float16)accs[nt][r];
        } else {
#pragma unroll
          for (int r = 0; r < 4; ++r)
            Ps[wv][(l4 * 4 + r) * 40 + h2 * 16 + l15] = (_Float16)0.f;
        }
      }
      half8 ap = *(const half8*)&Ps[wv][l15 * 40 + l4 * 8];
#pragma unroll
      for (int dt = 0; dt < 4; ++dt) {
        half8 bv = *(const half8*)&Vt[(dt * 16 + l15) * 232 + nsl * 32 + l4 * 8];
        acco[dt] = __builtin_amdgcn_mfma_f32_16x16x32_f16(ap, bv, acco[dt], 0, 0, 0);
      }
    }
#pragma unroll
    for (int dt = 0; dt < 4; ++dt) {
#pragma unroll
      for (int r = 0; r < 4; ++r) {
        const int m = mt * 16 + l4 * 4 + r;
        if (m < Nn)
          OUT[((size_t)b * Nn + m) * Cc + hh * Dh + dt * 16 + l15] = (_Float16)acco[dt][r];
      }
    }
  }
}

// ---------------------------------------------------------------------------
extern "C" void kernel_launch(void* const* d_in, const int* in_sizes, int n_in,
                              void* d_out, int out_size, void* d_ws, size_t ws_size,
                              hipStream_t stream) {
  const float* hidden = (const float*)d_in[0];
  const float* Wq = (const float*)d_in[1];
  const float* bq = (const float*)d_in[2];
  const float* dw_w = (const float*)d_in[3];
  const float* dw_b = (const float*)d_in[4];
  const float* ln_w = (const float*)d_in[5];
  const float* ln_b = (const float*)d_in[6];
  const float* pw_w = (const float*)d_in[7];
  const float* Wk = (const float*)d_in[8];
  const float* bk = (const float*)d_in[9];
  const float* Wv = (const float*)d_in[10];
  const float* bv = (const float*)d_in[11];
  const float* Wp = (const float*)d_in[12];
  const float* bp = (const float*)d_in[13];
  const float* Wo = (const float*)d_in[14];
  const float* bo = (const float*)d_in[15];

  const size_t SZ = (size_t)Bsz * Nn * Cc;      // 19,267,584
  float* yout = (float*)d_out;                  // (B,N,C) fp32
  float* attn = yout + SZ;                      // (B,12,196,196) fp32 probs

  _Float16* h16   = (_Float16*)d_ws;            // fp16 workspace buffers
  _Float16* Q16   = h16   + SZ;
  _Float16* XS16  = Q16   + SZ;
  _Float16* K16   = XS16  + SZ;
  _Float16* V16   = K16   + SZ;
  _Float16* OUT16 = V16   + SZ;
  _Float16* Y116  = OUT16 + SZ;
  _Float16* W16   = Y116  + SZ;                 // 5 x 768 x 768 (Wq,Wk,Wv,Wp,Wo)

  const int gemm_blocks = (ROWS / 128) * (Cc / 128);  // 1176
  const int kv_blocks   = (ROWS / 128) * 12;          // 2352
  const int n8 = (int)(SZ / 8);

  // 0. one-shot fp16 conversions
  cvt_f32_f16<<<(n8 + 255) / 256, 256, 0, stream>>>(hidden, h16, n8);
  cvt_w5<<<(5 * Cc * Cc / 8 + 255) / 256, 256, 0, stream>>>(Wq, Wk, Wv, Wp, Wo, W16);

  // 1. Q16 = hidden @ Wq^T + bq
  gemm_h16<1><<<gemm_blocks, 256, 0, stream>>>(h16, W16 + 0 * (size_t)Cc * Cc, bq, Q16);
  // 2. offset network + bilinear sampling -> XS16
  offset_sample<<<dim3(Gg, Bsz), 512, 0, stream>>>(Q16, hidden, dw_w, dw_b, ln_w, ln_b, pw_w, XS16);
  // 3. K16,V16 in one dispatch (stacked Wk||Wv, A staged once)
  gemm_h16_kv<<<kv_blocks, 256, 0, stream>>>(XS16, W16 + 1 * (size_t)Cc * Cc, bk, bv, K16, V16);
  // 4. fused scores+softmax+PV -> attn (fp32 probs) + OUT16
  attn_fused<<<dim3(NHh, Bsz), 512, 0, stream>>>(Q16, K16, V16, attn, OUT16);
  // 5. Y116 = OUT16 @ Wproj^T + bproj
  gemm_h16<1><<<gemm_blocks, 256, 0, stream>>>(OUT16, W16 + 3 * (size_t)Cc * Cc, bp, Y116);
  // 6. y = Y116 @ Wout^T + bout -> d_out (fp32)
  gemm_h16<0><<<gemm_blocks, 256, 0, stream>>>(Y116, W16 + 4 * (size_t)Cc * Cc, bo, yout);
}